// Round 7
// baseline (842.179 us; speedup 1.0000x reference)
//
#include <hip/hip_runtime.h>

// Problem constants (fixed by reference)
#define NN   50000
#define NNP  50048   // padded to 391*128
#define NE   800000
#define DIN  512
#define DH   512
#define DE   256

// CSR padded to multiple of 8 per node, sentinel = NN (dis[NN]=0, t'[NN]=0 row)
#define CSR_CAP 1150016  // >= NE + 7*NN, multiple of 16 ints

typedef __bf16 bf16_t;
typedef __bf16 bf16x4 __attribute__((ext_vector_type(4)));
typedef __bf16 bf16x8 __attribute__((ext_vector_type(8)));
typedef float  f32x4  __attribute__((ext_vector_type(4)));
typedef _Float16 half_t;
typedef _Float16 half8 __attribute__((ext_vector_type(8)));

// ---------------- fused prep kernel ----------------
#define PB_SPLIT 25024   // NNP*DIN/4/256 exactly
#define PB_IDEG  3125    // NE/256 exactly
#define PB_CSR   1124    // ceil(CSR_CAP/4/256)
#define PB_W1    1024    // 512*512/256
#define PB_W2    1024
#define PB_W3    512     // 512*256/256
#define PB_HEADW 80      // 80*256/256
#define PB_TOTAL (PB_SPLIT + PB_IDEG + PB_CSR + PB_W1 + PB_W2 + PB_W3 + PB_HEADW)

__global__ void k_prep(const float* __restrict__ X, bf16_t* __restrict__ Xh,
                       bf16_t* __restrict__ Xl, const int* __restrict__ dst,
                       int* __restrict__ indeg, int* __restrict__ csr,
                       const float* __restrict__ W1, bf16_t* __restrict__ B1h, bf16_t* __restrict__ B1l,
                       const float* __restrict__ W2, half_t* __restrict__ B2h, half_t* __restrict__ B2l,
                       const float* __restrict__ W3, half_t* __restrict__ B3h, half_t* __restrict__ B3l,
                       const float* __restrict__ We, const float* __restrict__ be,
                       const float* __restrict__ Wh, const float* __restrict__ bh,
                       const float* __restrict__ Wg, const float* __restrict__ bg,
                       bf16_t* __restrict__ Wth, bf16_t* __restrict__ Wtl,
                       float* __restrict__ bc, int* __restrict__ done) {
    int b = blockIdx.x;
    if (b < PB_SPLIT) {
        long idx = (long)b * 256 + threadIdx.x;      // < NNP*DIN/4
        long base = idx * 4;
        int row = (int)(base >> 9);                  // /DIN
        f32x4 v;
        if (row < NN) v = *(const f32x4*)(X + base);
        else { v[0] = 0.f; v[1] = 0.f; v[2] = 0.f; v[3] = 0.f; }
        bf16x4 h, l;
        #pragma unroll
        for (int c = 0; c < 4; ++c) {
            float f = v[c];
            bf16_t hh = (bf16_t)f;
            h[c] = hh;
            l[c] = (bf16_t)(f - (float)hh);
        }
        *(bf16x4*)(Xh + base) = h;
        *(bf16x4*)(Xl + base) = l;
        return;
    }
    b -= PB_SPLIT;
    if (b < PB_IDEG) {
        int i = b * 256 + threadIdx.x;               // NE exact
        atomicAdd(&indeg[dst[i]], 1);
        return;
    }
    b -= PB_IDEG;
    if (b < PB_CSR) {
        int i = b * 256 + threadIdx.x;
        if (i < CSR_CAP / 4) ((int4*)csr)[i] = make_int4(NN, NN, NN, NN);
        return;
    }
    b -= PB_CSR;
    if (b < PB_W1) {
        int idx = b * 256 + threadIdx.x;             // 512x512 exact
        int k = idx >> 9, n = idx & 511;
        float f = W1[idx];
        bf16_t h = (bf16_t)f;
        B1h[(size_t)n * DIN + k] = h;
        B1l[(size_t)n * DIN + k] = (bf16_t)(f - (float)h);
        return;
    }
    b -= PB_W1;
    if (b < PB_W2) {
        int idx = b * 256 + threadIdx.x;             // 512x512 exact
        int k = idx >> 9, n = idx & 511;
        float f = W2[idx];
        half_t h = (half_t)f;
        B2h[(size_t)n * DH + k] = h;
        B2l[(size_t)n * DH + k] = (half_t)((f - (float)h) * 4096.f);
        return;
    }
    b -= PB_W2;
    if (b < PB_W3) {
        int idx = b * 256 + threadIdx.x;             // 512x256 exact, W3[k][n]
        int k = idx >> 8, n = idx & 255;
        float f = W3[idx];
        half_t h = (half_t)f;
        B3h[(size_t)n * DH + k] = h;
        B3l[(size_t)n * DH + k] = (half_t)((f - (float)h) * 4096.f);
        return;
    }
    b -= PB_W3;
    {
        int idx = b * 256 + threadIdx.x;             // 80*256 exact
        int n = idx / 256, k = idx % 256;
        if (idx == 0) *done = 0;                     // reset scan barrier counter
        float f = 0.f;
        if (n < 7)       f = We[k * 7 + n];
        else if (n < 15) f = Wh[k * 8 + (n - 7)];
        else if (n < 72) f = Wg[k * 57 + (n - 15)];
        bf16_t h = (bf16_t)f;
        Wth[idx] = h;
        Wtl[idx] = (bf16_t)(f - (float)h);
        if (k == 0) {
            float bb = 0.f;
            if (n < 7)       bb = be[n];
            else if (n < 15) bb = bh[n - 7];
            else if (n < 72) bb = bg[n - 15];
            bc[n] = bb;
        }
    }
}

// ---------------- single-kernel parallel scan (49 all-resident blocks) ----------------
// Local scan -> post bsum -> atomic-counter barrier -> per-block offset -> final write.
#define SCAN_BLOCKS 49   // ceil(NN/1024); 49 blocks <= 256 CUs -> all resident, spin safe

__global__ __launch_bounds__(1024) void k_scan(const int* __restrict__ indeg,
                                               int* __restrict__ rowptr,
                                               int* __restrict__ cursor,
                                               float* __restrict__ dis,
                                               int* __restrict__ bsum,
                                               int* __restrict__ done) {
    __shared__ int wsum[16];
    __shared__ int s_off;
    const int tid = threadIdx.x, lane = tid & 63, wid = tid >> 6;
    const int i = blockIdx.x * 1024 + tid;
    int deg = (i < NN) ? indeg[i] : 0;
    int v = (deg + 7) & ~7;                          // pad segment to %8
    int x = v;
    #pragma unroll
    for (int d = 1; d < 64; d <<= 1) {
        int t = __shfl_up(x, d, 64);
        if (lane >= d) x += t;
    }
    if (lane == 63) wsum[wid] = x;
    __syncthreads();
    if (wid == 0) {
        int s = (lane < 16) ? wsum[lane] : 0;
        #pragma unroll
        for (int d = 1; d < 16; d <<= 1) {
            int t = __shfl_up(s, d, 64);
            if (lane >= d) s += t;
        }
        if (lane < 16) wsum[lane] = s;               // inclusive wave prefix
    }
    __syncthreads();
    int woff = (wid > 0) ? wsum[wid - 1] : 0;
    int incl = x + woff;                             // inclusive prefix within block
    int excl = incl - v;

    // post block total, barrier on all 49 blocks
    if (tid == 0) {
        bsum[blockIdx.x] = wsum[15];
        __threadfence();
        atomicAdd(done, 1);
        while (atomicAdd(done, 0) < SCAN_BLOCKS) { }
        __threadfence();
    }
    __syncthreads();

    // per-block exclusive offset from bsum
    if (wid == 0) {
        int bv = (lane < SCAN_BLOCKS) ? bsum[lane] : 0;
        int bx = bv;
        #pragma unroll
        for (int d = 1; d < 64; d <<= 1) {
            int t = __shfl_up(bx, d, 64);
            if (lane >= d) bx += t;
        }
        if (lane == (int)blockIdx.x) s_off = bx - bv;
    }
    __syncthreads();
    const int off = s_off;

    if (i < NN) {
        int r = off + excl;
        rowptr[i] = r;
        cursor[i] = r;
        dis[i] = rsqrtf((float)(deg + 1));
        if (i == NN - 1) rowptr[NN] = off + incl;    // grand total
    } else if (i < NNP) {
        dis[i] = 0.f;                                // pad rows (incl. sentinel NN)
    }
}

__global__ void k_fill(const int* __restrict__ src, const int* __restrict__ dst,
                       int* __restrict__ cursor, int* __restrict__ csr, int e) {
    int i = blockIdx.x * blockDim.x + threadIdx.x;
    if (i < e) {
        int d = dst[i];
        int p = atomicAdd(&cursor[d], 1);
        csr[p] = src[i];
    }
}

// ---------------- GEMM helpers ----------------

__device__ __forceinline__ void gld_lds16(const void* g, void* l) {
    __builtin_amdgcn_global_load_lds(
        (const __attribute__((address_space(1))) unsigned int*)g,
        (__attribute__((address_space(3))) unsigned int*)l, 16, 0, 0);
}

// LDS chunk swizzle: row r's 16B chunk q stored at slot q ^ ((r>>1)&3), applied
// by swizzling the GLOBAL source (dest linear per global_load_lds) and XORing
// the fragment-read chunk index.

// ---------------- layer-1 GEMM: 3-term split-bf16, dis-scaled fp16 out ----------------
// 8 waves (512 thr), 128x128 tile, BK=32; wave 32x64, acc shared across the 3 terms.
// Double-buffered LDS, stage-early 2-phase (structure from round 4/6).

__global__ __launch_bounds__(512) void k_gemm_bf3(
    const bf16_t* __restrict__ Ah, const bf16_t* __restrict__ Al,
    const bf16_t* __restrict__ Bh, const bf16_t* __restrict__ Bl,  // [N,K]
    const float* __restrict__ disv,
    half_t* __restrict__ C, int N, int K) {
    __shared__ alignas(16) bf16_t sAh[2][128 * 32];
    __shared__ alignas(16) bf16_t sAl[2][128 * 32];
    __shared__ alignas(16) bf16_t sBh[2][128 * 32];
    __shared__ alignas(16) bf16_t sBl[2][128 * 32];

    const int tid = threadIdx.x;
    const int wave = tid >> 6, lane = tid & 63;
    const int quad = lane >> 4, l16 = lane & 15;
    const int bm = blockIdx.y * 128, bn = blockIdx.x * 128;
    const int wm = (wave >> 1) * 32, wn = (wave & 1) * 64;

    f32x4 acc[2][4];
    #pragma unroll
    for (int i = 0; i < 2; ++i)
        #pragma unroll
        for (int j = 0; j < 4; ++j)
            #pragma unroll
            for (int r = 0; r < 4; ++r) acc[i][j][r] = 0.f;

    const int srow = tid >> 2;
    const int schk = ((tid & 3) ^ ((tid >> 3) & 3)) * 16;   // swizzled src chunk
    const unsigned ldso = (unsigned)wave * 1024;            // wave-uniform LDS base

    const char* gAh0 = (const char*)(Ah + (size_t)(bm + srow) * K) + schk;
    const char* gAl0 = (const char*)(Al + (size_t)(bm + srow) * K) + schk;
    const char* gBh0 = (const char*)(Bh + (size_t)(bn + srow) * K) + schk;
    const char* gBl0 = (const char*)(Bl + (size_t)(bn + srow) * K) + schk;

    const int rsw = (l16 >> 1) & 3;                  // read swizzle
    const int nsteps = K >> 5;

    gld_lds16(gAh0, (char*)sAh[0] + ldso);
    gld_lds16(gAl0, (char*)sAl[0] + ldso);
    gld_lds16(gBh0, (char*)sBh[0] + ldso);
    gld_lds16(gBl0, (char*)sBl[0] + ldso);
    __syncthreads();

    for (int t = 0; t < nsteps; ++t) {
        const int cur = t & 1;
        if (t + 1 < nsteps) {
            const size_t kb = (size_t)(t + 1) * 64;  // 32 elems * 2B
            const int nx = cur ^ 1;
            gld_lds16(gAh0 + kb, (char*)sAh[nx] + ldso);
            gld_lds16(gAl0 + kb, (char*)sAl[nx] + ldso);
            gld_lds16(gBh0 + kb, (char*)sBh[nx] + ldso);
            gld_lds16(gBl0 + kb, (char*)sBl[nx] + ldso);
        }
        bf16x8 fah[2], fal[2], fbh[4], fbl[4];
        #pragma unroll
        for (int i = 0; i < 2; ++i) {
            fah[i] = *(const bf16x8*)(sAh[cur] + (wm + 16 * i + l16) * 32 + (quad ^ rsw) * 8);
            fal[i] = *(const bf16x8*)(sAl[cur] + (wm + 16 * i + l16) * 32 + (quad ^ rsw) * 8);
        }
        #pragma unroll
        for (int j = 0; j < 4; ++j) {
            fbh[j] = *(const bf16x8*)(sBh[cur] + (wn + 16 * j + l16) * 32 + (quad ^ rsw) * 8);
            fbl[j] = *(const bf16x8*)(sBl[cur] + (wn + 16 * j + l16) * 32 + (quad ^ rsw) * 8);
        }
        #pragma unroll
        for (int i = 0; i < 2; ++i)
            #pragma unroll
            for (int j = 0; j < 4; ++j) {
                acc[i][j] = __builtin_amdgcn_mfma_f32_16x16x32_bf16(fah[i], fbh[j], acc[i][j], 0, 0, 0);
                acc[i][j] = __builtin_amdgcn_mfma_f32_16x16x32_bf16(fah[i], fbl[j], acc[i][j], 0, 0, 0);
                acc[i][j] = __builtin_amdgcn_mfma_f32_16x16x32_bf16(fal[i], fbh[j], acc[i][j], 0, 0, 0);
            }
        __syncthreads();
    }

    #pragma unroll
    for (int i = 0; i < 2; ++i) {
        const int rowb = bm + wm + 16 * i + quad * 4;
        float d0 = disv[rowb], d1 = disv[rowb + 1], d2 = disv[rowb + 2], d3 = disv[rowb + 3];
        #pragma unroll
        for (int j = 0; j < 4; ++j) {
            int col = bn + wn + 16 * j + l16;
            C[(size_t)(rowb + 0) * N + col] = (half_t)(acc[i][j][0] * d0);
            C[(size_t)(rowb + 1) * N + col] = (half_t)(acc[i][j][1] * d1);
            C[(size_t)(rowb + 2) * N + col] = (half_t)(acc[i][j][2] * d2);
            C[(size_t)(rowb + 3) * N + col] = (half_t)(acc[i][j][3] * d3);
        }
    }
}

// ---------------- layers 2-3 GEMM: 2-term fp16, TRIPLE-buffered counted-vmcnt ----------
// T4 pipeline: per step {vmcnt(3); s_barrier; issue stage(t+2); ds_read+MFMA}.
// vmcnt(3) BEFORE the barrier: each wave certifies its own stage(t) landed, the
// barrier publishes to all waves; stage(t+1)'s 3 loads stay in flight ACROSS the
// barrier (the counted-vmcnt gain the 2-phase drain forfeits). LDS 72KB -> 2 blk/CU.

__global__ __launch_bounds__(512) void k_gemm_f16(
    const half_t* __restrict__ A,
    const half_t* __restrict__ Bh, const half_t* __restrict__ Bl,  // [N,K]
    const float* __restrict__ disv,
    half_t* __restrict__ C, int N, int K) {
    __shared__ alignas(16) half_t sA [3][128 * 32];
    __shared__ alignas(16) half_t sBh[3][128 * 32];
    __shared__ alignas(16) half_t sBl[3][128 * 32];

    const int tid = threadIdx.x;
    const int wave = tid >> 6, lane = tid & 63;
    const int quad = lane >> 4, l16 = lane & 15;
    const int bm = blockIdx.y * 128, bn = blockIdx.x * 128;
    const int wm = (wave >> 1) * 32, wn = (wave & 1) * 64;

    f32x4 aH[2][4], aM[2][4];
    #pragma unroll
    for (int i = 0; i < 2; ++i)
        #pragma unroll
        for (int j = 0; j < 4; ++j)
            #pragma unroll
            for (int r = 0; r < 4; ++r) { aH[i][j][r] = 0.f; aM[i][j][r] = 0.f; }

    const int srow = tid >> 2;
    const int schk = ((tid & 3) ^ ((tid >> 3) & 3)) * 16;
    const unsigned ldso = (unsigned)wave * 1024;

    const char* gA0  = (const char*)(A  + (size_t)(bm + srow) * K) + schk;
    const char* gBh0 = (const char*)(Bh + (size_t)(bn + srow) * K) + schk;
    const char* gBl0 = (const char*)(Bl + (size_t)(bn + srow) * K) + schk;

    const int rsw = (l16 >> 1) & 3;
    const int nsteps = K >> 5;                       // 16

    // prologue: stage tiles 0 and 1 (6 loads in flight)
    gld_lds16(gA0,       (char*)sA      + ldso);
    gld_lds16(gBh0,      (char*)sBh     + ldso);
    gld_lds16(gBl0,      (char*)sBl     + ldso);
    gld_lds16(gA0  + 64, (char*)sA  + 8192 + ldso);
    gld_lds16(gBh0 + 64, (char*)sBh + 8192 + ldso);
    gld_lds16(gBl0 + 64, (char*)sBl + 8192 + ldso);

    int cur = 0, nx = 2;
    for (int t = 0; t < nsteps - 1; ++t) {
        // own stage(t) done (newest 3 = stage(t+1) may stay in flight), then publish
        asm volatile("s_waitcnt vmcnt(3)" ::: "memory");
        asm volatile("s_barrier" ::: "memory");
        if (t + 2 < nsteps) {
            const size_t kb = (size_t)(t + 2) * 64;
            gld_lds16(gA0  + kb, (char*)sA  + nx * 8192 + ldso);
            gld_lds16(gBh0 + kb, (char*)sBh + nx * 8192 + ldso);
            gld_lds16(gBl0 + kb, (char*)sBl + nx * 8192 + ldso);
        }
        const half_t* sAc  = (const half_t*)((const char*)sA  + cur * 8192);
        const half_t* sBhc = (const half_t*)((const char*)sBh + cur * 8192);
        const half_t* sBlc = (const half_t*)((const char*)sBl + cur * 8192);
        half8 fa[2], fbh[4], fbl[4];
        #pragma unroll
        for (int i = 0; i < 2; ++i)
            fa[i] = *(const half8*)(sAc + (wm + 16 * i + l16) * 32 + (quad ^ rsw) * 8);
        #pragma unroll
        for (int j = 0; j < 4; ++j) {
            fbh[j] = *(const half8*)(sBhc + (wn + 16 * j + l16) * 32 + (quad ^ rsw) * 8);
            fbl[j] = *(const half8*)(sBlc + (wn + 16 * j + l16) * 32 + (quad ^ rsw) * 8);
        }
        #pragma unroll
        for (int i = 0; i < 2; ++i)
            #pragma unroll
            for (int j = 0; j < 4; ++j) {
                aH[i][j] = __builtin_amdgcn_mfma_f32_16x16x32_f16(fa[i], fbh[j], aH[i][j], 0, 0, 0);
                aM[i][j] = __builtin_amdgcn_mfma_f32_16x16x32_f16(fa[i], fbl[j], aM[i][j], 0, 0, 0);
            }
        cur = (cur == 2) ? 0 : cur + 1;
        nx  = (nx  == 2) ? 0 : nx  + 1;
    }
    // final step: drain everything (stage(nsteps-1) has no newer loads behind it)
    asm volatile("s_waitcnt vmcnt(0)" ::: "memory");
    asm volatile("s_barrier" ::: "memory");
    {
        const half_t* sAc  = (const half_t*)((const char*)sA  + cur * 8192);
        const half_t* sBhc = (const half_t*)((const char*)sBh + cur * 8192);
        const half_t* sBlc = (const half_t*)((const char*)sBl + cur * 8192);
        half8 fa[2], fbh[4], fbl[4];
        #pragma unroll
        for (int i = 0; i < 2; ++i)
            fa[i] = *(const half8*)(sAc + (wm + 16 * i + l16) * 32 + (quad ^ rsw) * 8);
        #pragma unroll
        for (int j = 0; j < 4; ++j) {
            fbh[j] = *(const half8*)(sBhc + (wn + 16 * j + l16) * 32 + (quad ^ rsw) * 8);
            fbl[j] = *(const half8*)(sBlc + (wn + 16 * j + l16) * 32 + (quad ^ rsw) * 8);
        }
        #pragma unroll
        for (int i = 0; i < 2; ++i)
            #pragma unroll
            for (int j = 0; j < 4; ++j) {
                aH[i][j] = __builtin_amdgcn_mfma_f32_16x16x32_f16(fa[i], fbh[j], aH[i][j], 0, 0, 0);
                aM[i][j] = __builtin_amdgcn_mfma_f32_16x16x32_f16(fa[i], fbl[j], aM[i][j], 0, 0, 0);
            }
    }

    const float s = 1.f / 4096.f;
    #pragma unroll
    for (int i = 0; i < 2; ++i) {
        const int rowb = bm + wm + 16 * i + quad * 4;
        float d0 = disv[rowb], d1 = disv[rowb + 1], d2 = disv[rowb + 2], d3 = disv[rowb + 3];
        #pragma unroll
        for (int j = 0; j < 4; ++j) {
            int col = bn + wn + 16 * j + l16;
            C[(size_t)(rowb + 0) * N + col] = (half_t)(fmaf(aM[i][j][0], s, aH[i][j][0]) * d0);
            C[(size_t)(rowb + 1) * N + col] = (half_t)(fmaf(aM[i][j][1], s, aH[i][j][1]) * d1);
            C[(size_t)(rowb + 2) * N + col] = (half_t)(fmaf(aM[i][j][2], s, aH[i][j][2]) * d2);
            C[(size_t)(rowb + 3) * N + col] = (half_t)(fmaf(aM[i][j][3], s, aH[i][j][3]) * d3);
        }
    }
}

// ---------------- aggregation ----------------
// t' rows pre-scaled by dis[src]; out[i] = (sum t'[src] + t'[i])*dis[i] + b.
// CSR padded %8 with sentinel NN (t'[NN]=0 exactly).

// Layers 1-2: fused relu, single fp16 output (next GEMM A). D=512. 2 nodes/block.
__global__ __launch_bounds__(128) void k_agg16(
    const half_t* __restrict__ t, const int* __restrict__ rowptr,
    const int* __restrict__ csr, const float* __restrict__ dis,
    const float* __restrict__ bias, half_t* __restrict__ out) {
    const int node = blockIdx.x * 2 + (threadIdx.x >> 6);
    const int lane = threadIdx.x & 63;  // 64 lanes x 8 elems (16B loads)
    const int beg = rowptr[node], end = rowptr[node + 1];
    const float din = dis[node];
    const char* tc = (const char*)t;
    const unsigned lb = (unsigned)lane * 16u;

    float a0[8], a1[8], a2[8], a3[8];
    #pragma unroll
    for (int c = 0; c < 8; ++c) { a0[c] = 0.f; a1[c] = 0.f; a2[c] = 0.f; a3[c] = 0.f; }

    if (beg < end) {
        int4 sa = *(const int4*)(csr + beg);
        int4 sb = *(const int4*)(csr + beg + 4);
        half8 v0 = *(const half8*)(tc + (((unsigned)sa.x) << 10) + lb);
        half8 v1 = *(const half8*)(tc + (((unsigned)sa.y) << 10) + lb);
        half8 v2 = *(const half8*)(tc + (((unsigned)sa.z) << 10) + lb);
        half8 v3 = *(const half8*)(tc + (((unsigned)sa.w) << 10) + lb);
        half8 v4 = *(const half8*)(tc + (((unsigned)sb.x) << 10) + lb);
        half8 v5 = *(const half8*)(tc + (((unsigned)sb.y) << 10) + lb);
        half8 v6 = *(const half8*)(tc + (((unsigned)sb.z) << 10) + lb);
        half8 v7 = *(const half8*)(tc + (((unsigned)sb.w) << 10) + lb);
        int4 na = sa, nb = sb;
        if (beg + 8 < end) {
            na = *(const int4*)(csr + beg + 8);
            nb = *(const int4*)(csr + beg + 12);
        }
        for (int e = beg; e < end; ) {
            half8 u0 = v0, u1 = v1, u2 = v2, u3 = v3, u4 = v4, u5 = v5, u6 = v6, u7 = v7;
            e += 8;
            if (e < end) {
                v0 = *(const half8*)(tc + (((unsigned)na.x) << 10) + lb);
                v1 = *(const half8*)(tc + (((unsigned)na.y) << 10) + lb);
                v2 = *(const half8*)(tc + (((unsigned)na.z) << 10) + lb);
                v3 = *(const half8*)(tc + (((unsigned)na.w) << 10) + lb);
                v4 = *(const half8*)(tc + (((unsigned)nb.x) << 10) + lb);
                v5 = *(const half8*)(tc + (((unsigned)nb.y) << 10) + lb);
                v6 = *(const half8*)(tc + (((unsigned)nb.z) << 10) + lb);
                v7 = *(const half8*)(tc + (((unsigned)nb.w) << 10) + lb);
                if (e + 8 < end) {
                    na = *(const int4*)(csr + e + 8);
                    nb = *(const int4*)(csr + e + 12);
                }
            }
            #pragma unroll
            for (int c = 0; c < 8; ++c) {
                a0[c] = fmaf((float)u0[c], din, a0[c]);
                a1[c] = fmaf((float)u1[c], din, a1[c]);
                a2[c] = fmaf((float)u2[c], din, a2[c]);
                a3[c] = fmaf((float)u3[c], din, a3[c]);
                a0[c] = fmaf((float)u4[c], din, a0[c]);
                a1[c] = fmaf((float)u5[c], din, a1[c]);
                a2[c] = fmaf((float)u6[c], din, a2[c]);
                a3[c] = fmaf((float)u7[c], din, a3[c]);
            }
        }
    }

    half8 sv = ((const half8*)(t + (size_t)node * DH))[lane];
    f32x4 bv0 = ((const f32x4*)bias)[lane * 2];
    f32x4 bv1 = ((const f32x4*)bias)[lane * 2 + 1];
    half8 h;
    #pragma unroll
    for (int c = 0; c < 8; ++c) {
        float b = (c < 4) ? bv0[c] : bv1[c - 4];
        float acc = (a0[c] + a1[c]) + (a2[c] + a3[c]);
        float o = fmaf((float)sv[c], din, acc) + b;
        o = fmaxf(o, 0.f);
        h[c] = (half_t)o;
    }
    __builtin_nontemporal_store(h, (half8*)(out + (size_t)node * DH + lane * 8));
}

// Layer 3: fp32 emb only (heads split in-register now), no relu. D=256. 4 nodes/block.
__global__ __launch_bounds__(128) void k_agg_f32(
    const half_t* __restrict__ t, const int* __restrict__ rowptr,
    const int* __restrict__ csr, const float* __restrict__ dis,
    const float* __restrict__ bias, float* __restrict__ out) {
    const int node = blockIdx.x * 4 + (threadIdx.x >> 5);
    const int lane = threadIdx.x & 31;  // 32 lanes x 8 elems (16B loads)
    const int beg = rowptr[node], end = rowptr[node + 1];
    const float din = dis[node];
    const char* tc = (const char*)t;
    const unsigned lb = (unsigned)lane * 16u;

    float a0[8], a1[8], a2[8], a3[8];
    #pragma unroll
    for (int c = 0; c < 8; ++c) { a0[c] = 0.f; a1[c] = 0.f; a2[c] = 0.f; a3[c] = 0.f; }

    if (beg < end) {
        int4 sa = *(const int4*)(csr + beg);
        int4 sb = *(const int4*)(csr + beg + 4);
        half8 v0 = *(const half8*)(tc + (((unsigned)sa.x) << 9) + lb);
        half8 v1 = *(const half8*)(tc + (((unsigned)sa.y) << 9) + lb);
        half8 v2 = *(const half8*)(tc + (((unsigned)sa.z) << 9) + lb);
        half8 v3 = *(const half8*)(tc + (((unsigned)sa.w) << 9) + lb);
        half8 v4 = *(const half8*)(tc + (((unsigned)sb.x) << 9) + lb);
        half8 v5 = *(const half8*)(tc + (((unsigned)sb.y) << 9) + lb);
        half8 v6 = *(const half8*)(tc + (((unsigned)sb.z) << 9) + lb);
        half8 v7 = *(const half8*)(tc + (((unsigned)sb.w) << 9) + lb);
        int4 na = sa, nb = sb;
        if (beg + 8 < end) {
            na = *(const int4*)(csr + beg + 8);
            nb = *(const int4*)(csr + beg + 12);
        }
        for (int e = beg; e < end; ) {
            half8 u0 = v0, u1 = v1, u2 = v2, u3 = v3, u4 = v4, u5 = v5, u6 = v6, u7 = v7;
            e += 8;
            if (e < end) {
                v0 = *(const half8*)(tc + (((unsigned)na.x) << 9) + lb);
                v1 = *(const half8*)(tc + (((unsigned)na.y) << 9) + lb);
                v2 = *(const half8*)(tc + (((unsigned)na.z) << 9) + lb);
                v3 = *(const half8*)(tc + (((unsigned)na.w) << 9) + lb);
                v4 = *(const half8*)(tc + (((unsigned)nb.x) << 9) + lb);
                v5 = *(const half8*)(tc + (((unsigned)nb.y) << 9) + lb);
                v6 = *(const half8*)(tc + (((unsigned)nb.z) << 9) + lb);
                v7 = *(const half8*)(tc + (((unsigned)nb.w) << 9) + lb);
                if (e + 8 < end) {
                    na = *(const int4*)(csr + e + 8);
                    nb = *(const int4*)(csr + e + 12);
                }
            }
            #pragma unroll
            for (int c = 0; c < 8; ++c) {
                a0[c] = fmaf((float)u0[c], din, a0[c]);
                a1[c] = fmaf((float)u1[c], din, a1[c]);
                a2[c] = fmaf((float)u2[c], din, a2[c]);
                a3[c] = fmaf((float)u3[c], din, a3[c]);
                a0[c] = fmaf((float)u4[c], din, a0[c]);
                a1[c] = fmaf((float)u5[c], din, a1[c]);
                a2[c] = fmaf((float)u6[c], din, a2[c]);
                a3[c] = fmaf((float)u7[c], din, a3[c]);
            }
        }
    }

    half8 sv = ((const half8*)(t + (size_t)node * DE))[lane];
    f32x4 bv0 = ((const f32x4*)bias)[lane * 2];
    f32x4 bv1 = ((const f32x4*)bias)[lane * 2 + 1];
    f32x4 o0, o1;
    #pragma unroll
    for (int c = 0; c < 8; ++c) {
        float b = (c < 4) ? bv0[c] : bv1[c - 4];
        float acc = (a0[c] + a1[c]) + (a2[c] + a3[c]);
        float o = fmaf((float)sv[c], din, acc) + b;
        if (c < 4) o0[c] = o; else o1[c - 4] = o;
    }
    ((f32x4*)(out + (size_t)node * DE))[lane * 2]     = o0;
    ((f32x4*)(out + (size_t)node * DE))[lane * 2 + 1] = o1;
}

// ---------------- MFMA heads: emb fp32 -> in-register bf16 hi/lo split -> MFMA ----------
// Same math as the previous stored-split version (bit-identical values).

__global__ __launch_bounds__(256) void k_heads_mfma(
    const float* __restrict__ emb,
    const bf16_t* __restrict__ Wth, const bf16_t* __restrict__ Wtl,
    const float* __restrict__ bc,
    float* __restrict__ oe, float* __restrict__ oh, float* __restrict__ og) {
    const int wave = threadIdx.x >> 6, lane = threadIdx.x & 63;
    const int quad = lane >> 4, l16 = lane & 15;
    const int row0 = blockIdx.x * 64 + wave * 16;

    f32x4 acc[5];
    #pragma unroll
    for (int j = 0; j < 5; ++j)
        #pragma unroll
        for (int r = 0; r < 4; ++r) acc[j][r] = 0.f;

    const int arow = row0 + l16;
    const size_t abase = (size_t)((arow < NN) ? arow : 0) * 256 + quad * 8;  // clamp pad rows
    #pragma unroll
    for (int ks = 0; ks < 256; ks += 32) {
        f32x4 e0 = *(const f32x4*)(emb + abase + ks);
        f32x4 e1 = *(const f32x4*)(emb + abase + ks + 4);
        bf16x8 ah, al;
        #pragma unroll
        for (int c = 0; c < 4; ++c) {
            float f = e0[c];
            bf16_t h = (bf16_t)f;
            ah[c] = h;
            al[c] = (bf16_t)(f - (float)h);
            float g = e1[c];
            bf16_t h2 = (bf16_t)g;
            ah[4 + c] = h2;
            al[4 + c] = (bf16_t)(g - (float)h2);
        }
        #pragma unroll
        for (int j = 0; j < 5; ++j) {
            const size_t bbase = (size_t)(j * 16 + l16) * 256 + ks + quad * 8;
            bf16x8 bh = *(const bf16x8*)(Wth + bbase);
            bf16x8 bl = *(const bf16x8*)(Wtl + bbase);
            acc[j] = __builtin_amdgcn_mfma_f32_16x16x32_bf16(ah, bh, acc[j], 0, 0, 0);
            acc[j] = __builtin_amdgcn_mfma_f32_16x16x32_bf16(ah, bl, acc[j], 0, 0, 0);
            acc[j] = __builtin_amdgcn_mfma_f32_16x16x32_bf16(al, bh, acc[j], 0, 0, 0);
        }
    }

    #pragma unroll
    for (int j = 0; j < 5; ++j) {
        int col = j * 16 + l16;
        if (col < 72) {
            float b = bc[col];
            #pragma unroll
            for (int r = 0; r < 4; ++r) {
                int row = row0 + quad * 4 + r;
                if (row < NN) {
                    float v = acc[j][r] + b;
                    if (col < 7)       oe[(size_t)row * 7 + col] = v;
                    else if (col < 15) oh[(size_t)row * 8 + (col - 7)] = v;
                    else               og[(size_t)row * 57 + (col - 15)] = v;
                }
            }
        }
    }
}

// ---------------- launch ----------------

extern "C" void kernel_launch(void* const* d_in, const int* in_sizes, int n_in,
                              void* d_out, int out_size, void* d_ws, size_t ws_size,
                              hipStream_t stream) {
    const float* x   = (const float*)d_in[0];
    const int*   ei  = (const int*)d_in[1];
    const float* W1  = (const float*)d_in[2];
    const float* b1  = (const float*)d_in[3];
    const float* W2  = (const float*)d_in[4];
    const float* b2  = (const float*)d_in[5];
    const float* W3  = (const float*)d_in[6];
    const float* b3  = (const float*)d_in[7];
    const float* We  = (const float*)d_in[8];
    const float* be  = (const float*)d_in[9];
    const float* Wh  = (const float*)d_in[10];
    const float* bh  = (const float*)d_in[11];
    const float* Wg  = (const float*)d_in[12];
    const float* bg  = (const float*)d_in[13];

    const int* e_src = ei;
    const int* e_dst = ei + NE;

    // workspace layout (~162 MB, with aliasing)
    half_t* buf0 = (half_t*)d_ws;
    half_t* buf1 = buf0 + (size_t)NNP * DH;
    bf16_t* Xh   = (bf16_t*)buf1;
    bf16_t* Xl   = Xh + (size_t)NNP * DH;
    bf16_t* B1h  = Xl + (size_t)NNP * DH;
    bf16_t* B1l  = B1h + (size_t)DIN * DH;
    half_t* B2h  = (half_t*)(B1l + (size_t)DIN * DH);
    half_t* B2l  = B2h + (size_t)DH * DH;
    half_t* B3h  = B2l + (size_t)DH * DH;
    half_t* B3l  = B3h + (size_t)DE * DH;
    bf16_t* Wth  = (bf16_t*)(B3l + (size_t)DE * DH);
    bf16_t* Wtl  = Wth + 80 * 256;
    float*  bc   = (float*)(Wtl + 80 * 256);            // 80 fp32 (pad 128)
    int*   indeg  = (int*)(bc + 128);
    int*   rowptr = indeg + 50048;                      // 50001 used
    int*   cursor = rowptr + 50048;
    float* dis    = (float*)(cursor + 50048);           // NNP floats (pad+sentinel = 0)
    int*   csr    = (int*)(dis + 50048);                // CSR_CAP
    int*   bsum   = csr + CSR_CAP;                      // 64
    int*   done   = bsum + 64;                          // 1 (scan barrier counter)

    float* emb   = (float*)d_out;                       // 50000*256
    float* out_e = emb + (size_t)NN * DE;               // 50000*7
    float* out_h = out_e + (size_t)NN * 7;              // 50000*8
    float* out_g = out_h + (size_t)NN * 8;              // 50000*57

    // 1) prep: zero indeg, then all input-only transforms in one wide launch
    hipMemsetAsync(indeg, 0, NN * sizeof(int), stream);
    k_prep<<<PB_TOTAL, 256, 0, stream>>>(x, Xh, Xl, e_dst, indeg, csr,
                                         W1, B1h, B1l, W2, B2h, B2l, W3, B3h, B3l,
                                         We, be, Wh, bh, Wg, bg, Wth, Wtl, bc, done);
    // 2) single-kernel scan + CSR fill
    k_scan<<<SCAN_BLOCKS, 1024, 0, stream>>>(indeg, rowptr, cursor, dis, bsum, done);
    k_fill<<<(NE + 255) / 256, 256, 0, stream>>>(e_src, e_dst, cursor, csr, NE);

    const int gy = NNP / 128;  // 391

    // 3) layer 1: bf16 3-term GEMM (x split), dis-scaled fp16 out
    k_gemm_bf3<<<dim3(DH / 128, gy), 512, 0, stream>>>(Xh, Xl, B1h, B1l, dis, buf0, DH, DIN);
    k_agg16<<<NN / 2, 128, 0, stream>>>(buf0, rowptr, csr, dis, b1, buf1);

    // 4) layer 2: fp16 2-term GEMM (8-wave, 3-buf counted vmcnt), dis-scaled fp16 out
    k_gemm_f16<<<dim3(DH / 128, gy), 512, 0, stream>>>(buf1, B2h, B2l, dis, buf0, DH, DH);
    k_agg16<<<NN / 2, 128, 0, stream>>>(buf0, rowptr, csr, dis, b2, buf1);

    // 5) layer 3: fp16 2-term GEMM -> t3' (NNP x 256), then agg -> fp32 emb
    k_gemm_f16<<<dim3(DE / 128, gy), 512, 0, stream>>>(buf1, B3h, B3l, dis, buf0, DE, DH);
    k_agg_f32<<<NN / 4, 128, 0, stream>>>(buf0, rowptr, csr, dis, b3, emb);

    // 6) heads via MFMA (reads fp32 emb, splits in-register)
    k_heads_mfma<<<NNP / 64, 256, 0, stream>>>(emb, Wth, Wtl, bc, out_e, out_h, out_g);
}

// Round 9
// 812.185 us; speedup vs baseline: 1.0369x; 1.0369x over previous
//
#include <hip/hip_runtime.h>

// Problem constants (fixed by reference)
#define NN   50000
#define NNP  50048   // padded to 391*128
#define NE   800000
#define DIN  512
#define DH   512
#define DE   256

// CSR padded to multiple of 8 per node, sentinel = NN (dis[NN]=0, t'[NN]=0 row)
#define CSR_CAP 1150016  // >= NE + 7*NN, multiple of 16 ints

typedef __bf16 bf16_t;
typedef __bf16 bf16x8 __attribute__((ext_vector_type(8)));
typedef float  f32x4  __attribute__((ext_vector_type(4)));
typedef _Float16 half_t;
typedef _Float16 half4 __attribute__((ext_vector_type(4)));
typedef _Float16 half8 __attribute__((ext_vector_type(8)));

// ---------------- fused prep kernel ----------------
//   (a) X fp32 -> X fp16 (single stream; ~2^-11 rel err, attenuated through W2/W3)
//   (b) indegree atomics
//   (c) csr sentinel prefill
//   (d,e,f) W1/W2/W3 -> fp16 h + l*4096 transpose split (2-term f16 MFMA)
//   (g) combined head weights + bias (bf16)
#define PB_SPLIT 25024   // NNP*DIN/4/256 exactly
#define PB_IDEG  3125    // NE/256 exactly
#define PB_CSR   1124    // ceil(CSR_CAP/4/256)
#define PB_W1    1024    // 512*512/256
#define PB_W2    1024
#define PB_W3    512     // 512*256/256
#define PB_HEADW 80      // 80*256/256
#define PB_TOTAL (PB_SPLIT + PB_IDEG + PB_CSR + PB_W1 + PB_W2 + PB_W3 + PB_HEADW)

__global__ void k_prep(const float* __restrict__ X, half_t* __restrict__ Xf,
                       const int* __restrict__ dst,
                       int* __restrict__ indeg, int* __restrict__ csr,
                       const float* __restrict__ W1, half_t* __restrict__ B1h, half_t* __restrict__ B1l,
                       const float* __restrict__ W2, half_t* __restrict__ B2h, half_t* __restrict__ B2l,
                       const float* __restrict__ W3, half_t* __restrict__ B3h, half_t* __restrict__ B3l,
                       const float* __restrict__ We, const float* __restrict__ be,
                       const float* __restrict__ Wh, const float* __restrict__ bh,
                       const float* __restrict__ Wg, const float* __restrict__ bg,
                       bf16_t* __restrict__ Wth, bf16_t* __restrict__ Wtl,
                       float* __restrict__ bc, int* __restrict__ done) {
    int b = blockIdx.x;
    if (b < PB_SPLIT) {
        long idx = (long)b * 256 + threadIdx.x;      // < NNP*DIN/4
        long base = idx * 4;
        int row = (int)(base >> 9);                  // /DIN
        f32x4 v;
        if (row < NN) v = *(const f32x4*)(X + base);
        else { v[0] = 0.f; v[1] = 0.f; v[2] = 0.f; v[3] = 0.f; }
        half4 h;
        #pragma unroll
        for (int c = 0; c < 4; ++c) h[c] = (half_t)v[c];
        *(half4*)(Xf + base) = h;
        return;
    }
    b -= PB_SPLIT;
    if (b < PB_IDEG) {
        int i = b * 256 + threadIdx.x;               // NE exact
        atomicAdd(&indeg[dst[i]], 1);
        return;
    }
    b -= PB_IDEG;
    if (b < PB_CSR) {
        int i = b * 256 + threadIdx.x;
        if (i < CSR_CAP / 4) ((int4*)csr)[i] = make_int4(NN, NN, NN, NN);
        return;
    }
    b -= PB_CSR;
    if (b < PB_W1) {
        int idx = b * 256 + threadIdx.x;             // 512x512 exact
        int k = idx >> 9, n = idx & 511;
        float f = W1[idx];
        half_t h = (half_t)f;
        B1h[(size_t)n * DIN + k] = h;
        B1l[(size_t)n * DIN + k] = (half_t)((f - (float)h) * 4096.f);
        return;
    }
    b -= PB_W1;
    if (b < PB_W2) {
        int idx = b * 256 + threadIdx.x;             // 512x512 exact
        int k = idx >> 9, n = idx & 511;
        float f = W2[idx];
        half_t h = (half_t)f;
        B2h[(size_t)n * DH + k] = h;
        B2l[(size_t)n * DH + k] = (half_t)((f - (float)h) * 4096.f);
        return;
    }
    b -= PB_W2;
    if (b < PB_W3) {
        int idx = b * 256 + threadIdx.x;             // 512x256 exact, W3[k][n]
        int k = idx >> 8, n = idx & 255;
        float f = W3[idx];
        half_t h = (half_t)f;
        B3h[(size_t)n * DH + k] = h;
        B3l[(size_t)n * DH + k] = (half_t)((f - (float)h) * 4096.f);
        return;
    }
    b -= PB_W3;
    {
        int idx = b * 256 + threadIdx.x;             // 80*256 exact
        int n = idx / 256, k = idx % 256;
        if (idx == 0) *done = 0;                     // reset scan barrier counter
        float f = 0.f;
        if (n < 7)       f = We[k * 7 + n];
        else if (n < 15) f = Wh[k * 8 + (n - 7)];
        else if (n < 72) f = Wg[k * 57 + (n - 15)];
        bf16_t h = (bf16_t)f;
        Wth[idx] = h;
        Wtl[idx] = (bf16_t)(f - (float)h);
        if (k == 0) {
            float bb = 0.f;
            if (n < 7)       bb = be[n];
            else if (n < 15) bb = bh[n - 7];
            else if (n < 72) bb = bg[n - 15];
            bc[n] = bb;
        }
    }
}

// ---------------- single-kernel parallel scan (49 all-resident blocks) ----------------
#define SCAN_BLOCKS 49   // ceil(NN/1024); 49 blocks <= 256 CUs -> all resident, spin safe

__global__ __launch_bounds__(1024) void k_scan(const int* __restrict__ indeg,
                                               int* __restrict__ rowptr,
                                               int* __restrict__ cursor,
                                               float* __restrict__ dis,
                                               int* __restrict__ bsum,
                                               int* __restrict__ done) {
    __shared__ int wsum[16];
    __shared__ int s_off;
    const int tid = threadIdx.x, lane = tid & 63, wid = tid >> 6;
    const int i = blockIdx.x * 1024 + tid;
    int deg = (i < NN) ? indeg[i] : 0;
    int v = (deg + 7) & ~7;                          // pad segment to %8
    int x = v;
    #pragma unroll
    for (int d = 1; d < 64; d <<= 1) {
        int t = __shfl_up(x, d, 64);
        if (lane >= d) x += t;
    }
    if (lane == 63) wsum[wid] = x;
    __syncthreads();
    if (wid == 0) {
        int s = (lane < 16) ? wsum[lane] : 0;
        #pragma unroll
        for (int d = 1; d < 16; d <<= 1) {
            int t = __shfl_up(s, d, 64);
            if (lane >= d) s += t;
        }
        if (lane < 16) wsum[lane] = s;               // inclusive wave prefix
    }
    __syncthreads();
    int woff = (wid > 0) ? wsum[wid - 1] : 0;
    int incl = x + woff;                             // inclusive prefix within block
    int excl = incl - v;

    // post block total, barrier on all 49 blocks
    if (tid == 0) {
        bsum[blockIdx.x] = wsum[15];
        __threadfence();
        atomicAdd(done, 1);
        while (atomicAdd(done, 0) < SCAN_BLOCKS) { }
        __threadfence();
    }
    __syncthreads();

    // per-block exclusive offset from bsum
    if (wid == 0) {
        int bv = (lane < SCAN_BLOCKS) ? bsum[lane] : 0;
        int bx = bv;
        #pragma unroll
        for (int d = 1; d < 64; d <<= 1) {
            int t = __shfl_up(bx, d, 64);
            if (lane >= d) bx += t;
        }
        if (lane == (int)blockIdx.x) s_off = bx - bv;
    }
    __syncthreads();
    const int off = s_off;

    if (i < NN) {
        int r = off + excl;
        rowptr[i] = r;
        cursor[i] = r;
        dis[i] = rsqrtf((float)(deg + 1));
        if (i == NN - 1) rowptr[NN] = off + incl;    // grand total
    } else if (i < NNP) {
        dis[i] = 0.f;                                // pad rows (incl. sentinel NN)
    }
}

__global__ void k_fill(const int* __restrict__ src, const int* __restrict__ dst,
                       int* __restrict__ cursor, int* __restrict__ csr, int e) {
    int i = blockIdx.x * blockDim.x + threadIdx.x;
    if (i < e) {
        int d = dst[i];
        int p = atomicAdd(&cursor[d], 1);
        csr[p] = src[i];
    }
}

// ---------------- GEMM helpers ----------------

__device__ __forceinline__ void gld_lds16(const void* g, void* l) {
    __builtin_amdgcn_global_load_lds(
        (const __attribute__((address_space(1))) unsigned int*)g,
        (__attribute__((address_space(3))) unsigned int*)l, 16, 0, 0);
}

// LDS chunk swizzle: row r's 16B chunk q stored at slot q ^ ((r>>1)&3), applied
// by swizzling the GLOBAL source (dest linear per global_load_lds) and XORing
// the fragment-read chunk index.

// ---------------- all layers: 2-term fp16 GEMM, TRIPLE-buffered counted-vmcnt --------
// C = (A @ (Bh + Bl/4096)) * disv[row]; A fp16, Bh/Bl [N,K] fp16 (Bl pre-scaled 4096).
// T4 pipeline: per step {vmcnt(3); s_barrier; issue stage(t+2); ds_read+MFMA}.
// vmcnt(3) BEFORE the barrier: each wave certifies its own stage(t) landed; the
// barrier publishes to all waves; stage(t+1)'s 3 loads stay in flight ACROSS it.

__global__ __launch_bounds__(512) void k_gemm_f16(
    const half_t* __restrict__ A,
    const half_t* __restrict__ Bh, const half_t* __restrict__ Bl,  // [N,K]
    const float* __restrict__ disv,
    half_t* __restrict__ C, int N, int K) {
    __shared__ alignas(16) half_t sA [3][128 * 32];
    __shared__ alignas(16) half_t sBh[3][128 * 32];
    __shared__ alignas(16) half_t sBl[3][128 * 32];

    const int tid = threadIdx.x;
    const int wave = tid >> 6, lane = tid & 63;
    const int quad = lane >> 4, l16 = lane & 15;
    const int bm = blockIdx.y * 128, bn = blockIdx.x * 128;
    const int wm = (wave >> 1) * 32, wn = (wave & 1) * 64;

    f32x4 aH[2][4], aM[2][4];
    #pragma unroll
    for (int i = 0; i < 2; ++i)
        #pragma unroll
        for (int j = 0; j < 4; ++j)
            #pragma unroll
            for (int r = 0; r < 4; ++r) { aH[i][j][r] = 0.f; aM[i][j][r] = 0.f; }

    const int srow = tid >> 2;
    const int schk = ((tid & 3) ^ ((tid >> 3) & 3)) * 16;
    const unsigned ldso = (unsigned)wave * 1024;

    const char* gA0  = (const char*)(A  + (size_t)(bm + srow) * K) + schk;
    const char* gBh0 = (const char*)(Bh + (size_t)(bn + srow) * K) + schk;
    const char* gBl0 = (const char*)(Bl + (size_t)(bn + srow) * K) + schk;

    const int rsw = (l16 >> 1) & 3;
    const int nsteps = K >> 5;                       // 16 or 8

    // prologue: stage tiles 0 and 1 (6 loads in flight)
    gld_lds16(gA0,       (char*)sA      + ldso);
    gld_lds16(gBh0,      (char*)sBh     + ldso);
    gld_lds16(gBl0,      (char*)sBl     + ldso);
    gld_lds16(gA0  + 64, (char*)sA  + 8192 + ldso);
    gld_lds16(gBh0 + 64, (char*)sBh + 8192 + ldso);
    gld_lds16(gBl0 + 64, (char*)sBl + 8192 + ldso);

    int cur = 0, nx = 2;
    for (int t = 0; t < nsteps - 1; ++t) {
        // own stage(t) done (newest 3 = stage(t+1) may stay in flight), then publish
        asm volatile("s_waitcnt vmcnt(3)" ::: "memory");
        asm volatile("s_barrier" ::: "memory");
        if (t + 2 < nsteps) {
            const size_t kb = (size_t)(t + 2) * 64;
            gld_lds16(gA0  + kb, (char*)sA  + nx * 8192 + ldso);
            gld_lds16(gBh0 + kb, (char*)sBh + nx * 8192 + ldso);
            gld_lds16(gBl0 + kb, (char*)sBl + nx * 8192 + ldso);
        }
        const half_t* sAc  = (const half_t*)((const char*)sA  + cur * 8192);
        const half_t* sBhc = (const half_t*)((const char*)sBh + cur * 8192);
        const half_t* sBlc = (const half_t*)((const char*)sBl + cur * 8192);
        half8 fa[2], fbh[4], fbl[4];
        #pragma unroll
        for (int i = 0; i < 2; ++i)
            fa[i] = *(const half8*)(sAc + (wm + 16 * i + l16) * 32 + (quad ^ rsw) * 8);
        #pragma unroll
        for (int j = 0; j < 4; ++j) {
            fbh[j] = *(const half8*)(sBhc + (wn + 16 * j + l16) * 32 + (quad ^ rsw) * 8);
            fbl[j] = *(const half8*)(sBlc + (wn + 16 * j + l16) * 32 + (quad ^ rsw) * 8);
        }
        #pragma unroll
        for (int i = 0; i < 2; ++i)
            #pragma unroll
            for (int j = 0; j < 4; ++j) {
                aH[i][j] = __builtin_amdgcn_mfma_f32_16x16x32_f16(fa[i], fbh[j], aH[i][j], 0, 0, 0);
                aM[i][j] = __builtin_amdgcn_mfma_f32_16x16x32_f16(fa[i], fbl[j], aM[i][j], 0, 0, 0);
            }
        cur = (cur == 2) ? 0 : cur + 1;
        nx  = (nx  == 2) ? 0 : nx  + 1;
    }
    // final step: drain everything
    asm volatile("s_waitcnt vmcnt(0)" ::: "memory");
    asm volatile("s_barrier" ::: "memory");
    {
        const half_t* sAc  = (const half_t*)((const char*)sA  + cur * 8192);
        const half_t* sBhc = (const half_t*)((const char*)sBh + cur * 8192);
        const half_t* sBlc = (const half_t*)((const char*)sBl + cur * 8192);
        half8 fa[2], fbh[4], fbl[4];
        #pragma unroll
        for (int i = 0; i < 2; ++i)
            fa[i] = *(const half8*)(sAc + (wm + 16 * i + l16) * 32 + (quad ^ rsw) * 8);
        #pragma unroll
        for (int j = 0; j < 4; ++j) {
            fbh[j] = *(const half8*)(sBhc + (wn + 16 * j + l16) * 32 + (quad ^ rsw) * 8);
            fbl[j] = *(const half8*)(sBlc + (wn + 16 * j + l16) * 32 + (quad ^ rsw) * 8);
        }
        #pragma unroll
        for (int i = 0; i < 2; ++i)
            #pragma unroll
            for (int j = 0; j < 4; ++j) {
                aH[i][j] = __builtin_amdgcn_mfma_f32_16x16x32_f16(fa[i], fbh[j], aH[i][j], 0, 0, 0);
                aM[i][j] = __builtin_amdgcn_mfma_f32_16x16x32_f16(fa[i], fbl[j], aM[i][j], 0, 0, 0);
            }
    }

    const float s = 1.f / 4096.f;
    #pragma unroll
    for (int i = 0; i < 2; ++i) {
        const int rowb = bm + wm + 16 * i + quad * 4;
        float d0 = disv[rowb], d1 = disv[rowb + 1], d2 = disv[rowb + 2], d3 = disv[rowb + 3];
        #pragma unroll
        for (int j = 0; j < 4; ++j) {
            int col = bn + wn + 16 * j + l16;
            C[(size_t)(rowb + 0) * N + col] = (half_t)(fmaf(aM[i][j][0], s, aH[i][j][0]) * d0);
            C[(size_t)(rowb + 1) * N + col] = (half_t)(fmaf(aM[i][j][1], s, aH[i][j][1]) * d1);
            C[(size_t)(rowb + 2) * N + col] = (half_t)(fmaf(aM[i][j][2], s, aH[i][j][2]) * d2);
            C[(size_t)(rowb + 3) * N + col] = (half_t)(fmaf(aM[i][j][3], s, aH[i][j][3]) * d3);
        }
    }
}

// ---------------- aggregation ----------------
// t' rows pre-scaled by dis[src]; out[i] = (sum t'[src] + t'[i])*dis[i] + b.
// CSR padded %8 with sentinel NN (t'[NN]=0 exactly).

// Layers 1-2: fused relu, single fp16 output (next GEMM A). D=512. 2 nodes/block.
__global__ __launch_bounds__(128) void k_agg16(
    const half_t* __restrict__ t, const int* __restrict__ rowptr,
    const int* __restrict__ csr, const float* __restrict__ dis,
    const float* __restrict__ bias, half_t* __restrict__ out) {
    const int node = blockIdx.x * 2 + (threadIdx.x >> 6);
    const int lane = threadIdx.x & 63;  // 64 lanes x 8 elems (16B loads)
    const int beg = rowptr[node], end = rowptr[node + 1];
    const float din = dis[node];
    const char* tc = (const char*)t;
    const unsigned lb = (unsigned)lane * 16u;

    float a0[8], a1[8], a2[8], a3[8];
    #pragma unroll
    for (int c = 0; c < 8; ++c) { a0[c] = 0.f; a1[c] = 0.f; a2[c] = 0.f; a3[c] = 0.f; }

    if (beg < end) {
        int4 sa = *(const int4*)(csr + beg);
        int4 sb = *(const int4*)(csr + beg + 4);
        half8 v0 = *(const half8*)(tc + (((unsigned)sa.x) << 10) + lb);
        half8 v1 = *(const half8*)(tc + (((unsigned)sa.y) << 10) + lb);
        half8 v2 = *(const half8*)(tc + (((unsigned)sa.z) << 10) + lb);
        half8 v3 = *(const half8*)(tc + (((unsigned)sa.w) << 10) + lb);
        half8 v4 = *(const half8*)(tc + (((unsigned)sb.x) << 10) + lb);
        half8 v5 = *(const half8*)(tc + (((unsigned)sb.y) << 10) + lb);
        half8 v6 = *(const half8*)(tc + (((unsigned)sb.z) << 10) + lb);
        half8 v7 = *(const half8*)(tc + (((unsigned)sb.w) << 10) + lb);
        int4 na = sa, nb = sb;
        if (beg + 8 < end) {
            na = *(const int4*)(csr + beg + 8);
            nb = *(const int4*)(csr + beg + 12);
        }
        for (int e = beg; e < end; ) {
            half8 u0 = v0, u1 = v1, u2 = v2, u3 = v3, u4 = v4, u5 = v5, u6 = v6, u7 = v7;
            e += 8;
            if (e < end) {
                v0 = *(const half8*)(tc + (((unsigned)na.x) << 10) + lb);
                v1 = *(const half8*)(tc + (((unsigned)na.y) << 10) + lb);
                v2 = *(const half8*)(tc + (((unsigned)na.z) << 10) + lb);
                v3 = *(const half8*)(tc + (((unsigned)na.w) << 10) + lb);
                v4 = *(const half8*)(tc + (((unsigned)nb.x) << 10) + lb);
                v5 = *(const half8*)(tc + (((unsigned)nb.y) << 10) + lb);
                v6 = *(const half8*)(tc + (((unsigned)nb.z) << 10) + lb);
                v7 = *(const half8*)(tc + (((unsigned)nb.w) << 10) + lb);
                if (e + 8 < end) {
                    na = *(const int4*)(csr + e + 8);
                    nb = *(const int4*)(csr + e + 12);
                }
            }
            #pragma unroll
            for (int c = 0; c < 8; ++c) {
                a0[c] = fmaf((float)u0[c], din, a0[c]);
                a1[c] = fmaf((float)u1[c], din, a1[c]);
                a2[c] = fmaf((float)u2[c], din, a2[c]);
                a3[c] = fmaf((float)u3[c], din, a3[c]);
                a0[c] = fmaf((float)u4[c], din, a0[c]);
                a1[c] = fmaf((float)u5[c], din, a1[c]);
                a2[c] = fmaf((float)u6[c], din, a2[c]);
                a3[c] = fmaf((float)u7[c], din, a3[c]);
            }
        }
    }

    half8 sv = ((const half8*)(t + (size_t)node * DH))[lane];
    f32x4 bv0 = ((const f32x4*)bias)[lane * 2];
    f32x4 bv1 = ((const f32x4*)bias)[lane * 2 + 1];
    half8 h;
    #pragma unroll
    for (int c = 0; c < 8; ++c) {
        float b = (c < 4) ? bv0[c] : bv1[c - 4];
        float acc = (a0[c] + a1[c]) + (a2[c] + a3[c]);
        float o = fmaf((float)sv[c], din, acc) + b;
        o = fmaxf(o, 0.f);
        h[c] = (half_t)o;
    }
    __builtin_nontemporal_store(h, (half8*)(out + (size_t)node * DH + lane * 8));
}

// Layer 3: fp32 emb only (heads split in-register), no relu. D=256. 4 nodes/block.
__global__ __launch_bounds__(128) void k_agg_f32(
    const half_t* __restrict__ t, const int* __restrict__ rowptr,
    const int* __restrict__ csr, const float* __restrict__ dis,
    const float* __restrict__ bias, float* __restrict__ out) {
    const int node = blockIdx.x * 4 + (threadIdx.x >> 5);
    const int lane = threadIdx.x & 31;  // 32 lanes x 8 elems (16B loads)
    const int beg = rowptr[node], end = rowptr[node + 1];
    const float din = dis[node];
    const char* tc = (const char*)t;
    const unsigned lb = (unsigned)lane * 16u;

    float a0[8], a1[8], a2[8], a3[8];
    #pragma unroll
    for (int c = 0; c < 8; ++c) { a0[c] = 0.f; a1[c] = 0.f; a2[c] = 0.f; a3[c] = 0.f; }

    if (beg < end) {
        int4 sa = *(const int4*)(csr + beg);
        int4 sb = *(const int4*)(csr + beg + 4);
        half8 v0 = *(const half8*)(tc + (((unsigned)sa.x) << 9) + lb);
        half8 v1 = *(const half8*)(tc + (((unsigned)sa.y) << 9) + lb);
        half8 v2 = *(const half8*)(tc + (((unsigned)sa.z) << 9) + lb);
        half8 v3 = *(const half8*)(tc + (((unsigned)sa.w) << 9) + lb);
        half8 v4 = *(const half8*)(tc + (((unsigned)sb.x) << 9) + lb);
        half8 v5 = *(const half8*)(tc + (((unsigned)sb.y) << 9) + lb);
        half8 v6 = *(const half8*)(tc + (((unsigned)sb.z) << 9) + lb);
        half8 v7 = *(const half8*)(tc + (((unsigned)sb.w) << 9) + lb);
        int4 na = sa, nb = sb;
        if (beg + 8 < end) {
            na = *(const int4*)(csr + beg + 8);
            nb = *(const int4*)(csr + beg + 12);
        }
        for (int e = beg; e < end; ) {
            half8 u0 = v0, u1 = v1, u2 = v2, u3 = v3, u4 = v4, u5 = v5, u6 = v6, u7 = v7;
            e += 8;
            if (e < end) {
                v0 = *(const half8*)(tc + (((unsigned)na.x) << 9) + lb);
                v1 = *(const half8*)(tc + (((unsigned)na.y) << 9) + lb);
                v2 = *(const half8*)(tc + (((unsigned)na.z) << 9) + lb);
                v3 = *(const half8*)(tc + (((unsigned)na.w) << 9) + lb);
                v4 = *(const half8*)(tc + (((unsigned)nb.x) << 9) + lb);
                v5 = *(const half8*)(tc + (((unsigned)nb.y) << 9) + lb);
                v6 = *(const half8*)(tc + (((unsigned)nb.z) << 9) + lb);
                v7 = *(const half8*)(tc + (((unsigned)nb.w) << 9) + lb);
                if (e + 8 < end) {
                    na = *(const int4*)(csr + e + 8);
                    nb = *(const int4*)(csr + e + 12);
                }
            }
            #pragma unroll
            for (int c = 0; c < 8; ++c) {
                a0[c] = fmaf((float)u0[c], din, a0[c]);
                a1[c] = fmaf((float)u1[c], din, a1[c]);
                a2[c] = fmaf((float)u2[c], din, a2[c]);
                a3[c] = fmaf((float)u3[c], din, a3[c]);
                a0[c] = fmaf((float)u4[c], din, a0[c]);
                a1[c] = fmaf((float)u5[c], din, a1[c]);
                a2[c] = fmaf((float)u6[c], din, a2[c]);
                a3[c] = fmaf((float)u7[c], din, a3[c]);
            }
        }
    }

    half8 sv = ((const half8*)(t + (size_t)node * DE))[lane];
    f32x4 bv0 = ((const f32x4*)bias)[lane * 2];
    f32x4 bv1 = ((const f32x4*)bias)[lane * 2 + 1];
    f32x4 o0, o1;
    #pragma unroll
    for (int c = 0; c < 8; ++c) {
        float b = (c < 4) ? bv0[c] : bv1[c - 4];
        float acc = (a0[c] + a1[c]) + (a2[c] + a3[c]);
        float o = fmaf((float)sv[c], din, acc) + b;
        if (c < 4) o0[c] = o; else o1[c - 4] = o;
    }
    ((f32x4*)(out + (size_t)node * DE))[lane * 2]     = o0;
    ((f32x4*)(out + (size_t)node * DE))[lane * 2 + 1] = o1;
}

// ---------------- MFMA heads: emb fp32 -> in-register bf16 hi/lo split -> MFMA ----------

__global__ __launch_bounds__(256) void k_heads_mfma(
    const float* __restrict__ emb,
    const bf16_t* __restrict__ Wth, const bf16_t* __restrict__ Wtl,
    const float* __restrict__ bc,
    float* __restrict__ oe, float* __restrict__ oh, float* __restrict__ og) {
    const int wave = threadIdx.x >> 6, lane = threadIdx.x & 63;
    const int quad = lane >> 4, l16 = lane & 15;
    const int row0 = blockIdx.x * 64 + wave * 16;

    f32x4 acc[5];
    #pragma unroll
    for (int j = 0; j < 5; ++j)
        #pragma unroll
        for (int r = 0; r < 4; ++r) acc[j][r] = 0.f;

    const int arow = row0 + l16;
    const size_t abase = (size_t)((arow < NN) ? arow : 0) * 256 + quad * 8;  // clamp pad rows
    #pragma unroll
    for (int ks = 0; ks < 256; ks += 32) {
        f32x4 e0 = *(const f32x4*)(emb + abase + ks);
        f32x4 e1 = *(const f32x4*)(emb + abase + ks + 4);
        bf16x8 ah, al;
        #pragma unroll
        for (int c = 0; c < 4; ++c) {
            float f = e0[c];
            bf16_t h = (bf16_t)f;
            ah[c] = h;
            al[c] = (bf16_t)(f - (float)h);
            float g = e1[c];
            bf16_t h2 = (bf16_t)g;
            ah[4 + c] = h2;
            al[4 + c] = (bf16_t)(g - (float)h2);
        }
        #pragma unroll
        for (int j = 0; j < 5; ++j) {
            const size_t bbase = (size_t)(j * 16 + l16) * 256 + ks + quad * 8;
            bf16x8 bh = *(const bf16x8*)(Wth + bbase);
            bf16x8 bl = *(const bf16x8*)(Wtl + bbase);
            acc[j] = __builtin_amdgcn_mfma_f32_16x16x32_bf16(ah, bh, acc[j], 0, 0, 0);
            acc[j] = __builtin_amdgcn_mfma_f32_16x16x32_bf16(ah, bl, acc[j], 0, 0, 0);
            acc[j] = __builtin_amdgcn_mfma_f32_16x16x32_bf16(al, bh, acc[j], 0, 0, 0);
        }
    }

    #pragma unroll
    for (int j = 0; j < 5; ++j) {
        int col = j * 16 + l16;
        if (col < 72) {
            float b = bc[col];
            #pragma unroll
            for (int r = 0; r < 4; ++r) {
                int row = row0 + quad * 4 + r;
                if (row < NN) {
                    float v = acc[j][r] + b;
                    if (col < 7)       oe[(size_t)row * 7 + col] = v;
                    else if (col < 15) oh[(size_t)row * 8 + (col - 7)] = v;
                    else               og[(size_t)row * 57 + (col - 15)] = v;
                }
            }
        }
    }
}

// ---------------- launch ----------------

extern "C" void kernel_launch(void* const* d_in, const int* in_sizes, int n_in,
                              void* d_out, int out_size, void* d_ws, size_t ws_size,
                              hipStream_t stream) {
    const float* x   = (const float*)d_in[0];
    const int*   ei  = (const int*)d_in[1];
    const float* W1  = (const float*)d_in[2];
    const float* b1  = (const float*)d_in[3];
    const float* W2  = (const float*)d_in[4];
    const float* b2  = (const float*)d_in[5];
    const float* W3  = (const float*)d_in[6];
    const float* b3  = (const float*)d_in[7];
    const float* We  = (const float*)d_in[8];
    const float* be  = (const float*)d_in[9];
    const float* Wh  = (const float*)d_in[10];
    const float* bh  = (const float*)d_in[11];
    const float* Wg  = (const float*)d_in[12];
    const float* bg  = (const float*)d_in[13];

    const int* e_src = ei;
    const int* e_dst = ei + NE;

    // workspace layout (~113 MB):
    //   buf0: GEMM outputs t' (fp16 NNP x 512)
    //   buf1: Xf16 (prep), then agg outputs / next GEMM A (fp16) -- X dead after GEMM1
    half_t* buf0 = (half_t*)d_ws;
    half_t* buf1 = buf0 + (size_t)NNP * DH;
    half_t* B1h  = buf1 + (size_t)NNP * DH;             // [512,512] f16 each
    half_t* B1l  = B1h + (size_t)DIN * DH;
    half_t* B2h  = B1l + (size_t)DIN * DH;
    half_t* B2l  = B2h + (size_t)DH * DH;
    half_t* B3h  = B2l + (size_t)DH * DH;               // [256,512] f16 each
    half_t* B3l  = B3h + (size_t)DE * DH;
    bf16_t* Wth  = (bf16_t*)(B3l + (size_t)DE * DH);
    bf16_t* Wtl  = Wth + 80 * 256;
    float*  bc   = (float*)(Wtl + 80 * 256);            // 80 fp32 (pad 128)
    int*   indeg  = (int*)(bc + 128);
    int*   rowptr = indeg + 50048;                      // 50001 used
    int*   cursor = rowptr + 50048;
    float* dis    = (float*)(cursor + 50048);           // NNP floats (pad+sentinel = 0)
    int*   csr    = (int*)(dis + 50048);                // CSR_CAP
    int*   bsum   = csr + CSR_CAP;                      // 64
    int*   done   = bsum + 64;                          // 1 (scan barrier counter)

    float* emb   = (float*)d_out;                       // 50000*256
    float* out_e = emb + (size_t)NN * DE;               // 50000*7
    float* out_h = out_e + (size_t)NN * 7;              // 50000*8
    float* out_g = out_h + (size_t)NN * 8;              // 50000*57

    // 1) prep: zero indeg, then all input-only transforms in one wide launch
    hipMemsetAsync(indeg, 0, NN * sizeof(int), stream);
    k_prep<<<PB_TOTAL, 256, 0, stream>>>(x, buf1, e_dst, indeg, csr,
                                         W1, B1h, B1l, W2, B2h, B2l, W3, B3h, B3l,
                                         We, be, Wh, bh, Wg, bg, Wth, Wtl, bc, done);
    // 2) single-kernel scan + CSR fill
    k_scan<<<SCAN_BLOCKS, 1024, 0, stream>>>(indeg, rowptr, cursor, dis, bsum, done);
    k_fill<<<(NE + 255) / 256, 256, 0, stream>>>(e_src, e_dst, cursor, csr, NE);

    const int gy = NNP / 128;  // 391

    // 3) layer 1: fp16 2-term GEMM (X fp16 single-stream), dis-scaled fp16 out
    k_gemm_f16<<<dim3(DH / 128, gy), 512, 0, stream>>>(buf1, B1h, B1l, dis, buf0, DH, DIN);
    k_agg16<<<NN / 2, 128, 0, stream>>>(buf0, rowptr, csr, dis, b1, buf1);

    // 4) layer 2: fp16 2-term GEMM, dis-scaled fp16 out
    k_gemm_f16<<<dim3(DH / 128, gy), 512, 0, stream>>>(buf1, B2h, B2l, dis, buf0, DH, DH);
    k_agg16<<<NN / 2, 128, 0, stream>>>(buf0, rowptr, csr, dis, b2, buf1);

    // 5) layer 3: fp16 2-term GEMM -> t3' (NNP x 256), then agg -> fp32 emb
    k_gemm_f16<<<dim3(DE / 128, gy), 512, 0, stream>>>(buf1, B3h, B3l, dis, buf0, DE, DH);
    k_agg_f32<<<NN / 4, 128, 0, stream>>>(buf0, rowptr, csr, dis, b3, emb);

    // 6) heads via MFMA (reads fp32 emb, splits in-register)
    k_heads_mfma<<<NNP / 64, 256, 0, stream>>>(emb, Wth, Wtl, bc, out_e, out_h, out_g);
}

// Round 10
// 746.544 us; speedup vs baseline: 1.1281x; 1.0879x over previous
//
#include <hip/hip_runtime.h>

// Problem constants (fixed by reference)
#define NN   50000
#define NNP  50048   // padded to 391*128
#define NE   800000
#define DIN  512
#define DH   512
#define DE   256

// CSR padded to multiple of 8 per node, sentinel = NN (dis[NN]=0, t'[NN]=0 row)
#define CSR_CAP 1150016  // >= NE + 7*NN, multiple of 16 ints

typedef __bf16 bf16_t;
typedef __bf16 bf16x8 __attribute__((ext_vector_type(8)));
typedef float  f32x4  __attribute__((ext_vector_type(4)));
typedef _Float16 half_t;
typedef _Float16 half4 __attribute__((ext_vector_type(4)));
typedef _Float16 half8 __attribute__((ext_vector_type(8)));

// ---------------- fused prep kernel ----------------
//   (a) X fp32 -> X fp16 (single stream)
//   (b) indegree atomics
//   (c) csr sentinel prefill
//   (d,e,f) W1/W2/W3 -> fp16 transpose (single stream; fp16-ulp W error is below
//           the t'-fp16 storage error floor established by rounds 8-9)
//   (g) combined head weights + bias (bf16 hi/lo, full precision for fp32 outputs)
#define PB_SPLIT 25024   // NNP*DIN/4/256 exactly
#define PB_IDEG  3125    // NE/256 exactly
#define PB_CSR   1124    // ceil(CSR_CAP/4/256)
#define PB_W1    1024    // 512*512/256
#define PB_W2    1024
#define PB_W3    512     // 512*256/256
#define PB_HEADW 80      // 80*256/256
#define PB_TOTAL (PB_SPLIT + PB_IDEG + PB_CSR + PB_W1 + PB_W2 + PB_W3 + PB_HEADW)

__global__ void k_prep(const float* __restrict__ X, half_t* __restrict__ Xf,
                       const int* __restrict__ dst,
                       int* __restrict__ indeg, int* __restrict__ csr,
                       const float* __restrict__ W1, half_t* __restrict__ B1h,
                       const float* __restrict__ W2, half_t* __restrict__ B2h,
                       const float* __restrict__ W3, half_t* __restrict__ B3h,
                       const float* __restrict__ We, const float* __restrict__ be,
                       const float* __restrict__ Wh, const float* __restrict__ bh,
                       const float* __restrict__ Wg, const float* __restrict__ bg,
                       bf16_t* __restrict__ Wth, bf16_t* __restrict__ Wtl,
                       float* __restrict__ bc, int* __restrict__ done) {
    int b = blockIdx.x;
    if (b < PB_SPLIT) {
        long idx = (long)b * 256 + threadIdx.x;      // < NNP*DIN/4
        long base = idx * 4;
        int row = (int)(base >> 9);                  // /DIN
        f32x4 v;
        if (row < NN) v = *(const f32x4*)(X + base);
        else { v[0] = 0.f; v[1] = 0.f; v[2] = 0.f; v[3] = 0.f; }
        half4 h;
        #pragma unroll
        for (int c = 0; c < 4; ++c) h[c] = (half_t)v[c];
        *(half4*)(Xf + base) = h;
        return;
    }
    b -= PB_SPLIT;
    if (b < PB_IDEG) {
        int i = b * 256 + threadIdx.x;               // NE exact
        atomicAdd(&indeg[dst[i]], 1);
        return;
    }
    b -= PB_IDEG;
    if (b < PB_CSR) {
        int i = b * 256 + threadIdx.x;
        if (i < CSR_CAP / 4) ((int4*)csr)[i] = make_int4(NN, NN, NN, NN);
        return;
    }
    b -= PB_CSR;
    if (b < PB_W1) {
        int idx = b * 256 + threadIdx.x;             // 512x512 exact
        int k = idx >> 9, n = idx & 511;
        B1h[(size_t)n * DIN + k] = (half_t)W1[idx];
        return;
    }
    b -= PB_W1;
    if (b < PB_W2) {
        int idx = b * 256 + threadIdx.x;             // 512x512 exact
        int k = idx >> 9, n = idx & 511;
        B2h[(size_t)n * DH + k] = (half_t)W2[idx];
        return;
    }
    b -= PB_W2;
    if (b < PB_W3) {
        int idx = b * 256 + threadIdx.x;             // 512x256 exact, W3[k][n]
        int k = idx >> 8, n = idx & 255;
        B3h[(size_t)n * DH + k] = (half_t)W3[idx];
        return;
    }
    b -= PB_W3;
    {
        int idx = b * 256 + threadIdx.x;             // 80*256 exact
        int n = idx / 256, k = idx % 256;
        if (idx == 0) *done = 0;                     // reset scan barrier counter
        float f = 0.f;
        if (n < 7)       f = We[k * 7 + n];
        else if (n < 15) f = Wh[k * 8 + (n - 7)];
        else if (n < 72) f = Wg[k * 57 + (n - 15)];
        bf16_t h = (bf16_t)f;
        Wth[idx] = h;
        Wtl[idx] = (bf16_t)(f - (float)h);
        if (k == 0) {
            float bb = 0.f;
            if (n < 7)       bb = be[n];
            else if (n < 15) bb = bh[n - 7];
            else if (n < 72) bb = bg[n - 15];
            bc[n] = bb;
        }
    }
}

// ---------------- single-kernel parallel scan (49 all-resident blocks) ----------------
#define SCAN_BLOCKS 49   // ceil(NN/1024); 49 blocks <= 256 CUs -> all resident, spin safe

__global__ __launch_bounds__(1024) void k_scan(const int* __restrict__ indeg,
                                               int* __restrict__ rowptr,
                                               int* __restrict__ cursor,
                                               float* __restrict__ dis,
                                               int* __restrict__ bsum,
                                               int* __restrict__ done) {
    __shared__ int wsum[16];
    __shared__ int s_off;
    const int tid = threadIdx.x, lane = tid & 63, wid = tid >> 6;
    const int i = blockIdx.x * 1024 + tid;
    int deg = (i < NN) ? indeg[i] : 0;
    int v = (deg + 7) & ~7;                          // pad segment to %8
    int x = v;
    #pragma unroll
    for (int d = 1; d < 64; d <<= 1) {
        int t = __shfl_up(x, d, 64);
        if (lane >= d) x += t;
    }
    if (lane == 63) wsum[wid] = x;
    __syncthreads();
    if (wid == 0) {
        int s = (lane < 16) ? wsum[lane] : 0;
        #pragma unroll
        for (int d = 1; d < 16; d <<= 1) {
            int t = __shfl_up(s, d, 64);
            if (lane >= d) s += t;
        }
        if (lane < 16) wsum[lane] = s;               // inclusive wave prefix
    }
    __syncthreads();
    int woff = (wid > 0) ? wsum[wid - 1] : 0;
    int incl = x + woff;                             // inclusive prefix within block
    int excl = incl - v;

    // post block total, barrier on all 49 blocks
    if (tid == 0) {
        bsum[blockIdx.x] = wsum[15];
        __threadfence();
        atomicAdd(done, 1);
        while (atomicAdd(done, 0) < SCAN_BLOCKS) { }
        __threadfence();
    }
    __syncthreads();

    // per-block exclusive offset from bsum
    if (wid == 0) {
        int bv = (lane < SCAN_BLOCKS) ? bsum[lane] : 0;
        int bx = bv;
        #pragma unroll
        for (int d = 1; d < 64; d <<= 1) {
            int t = __shfl_up(bx, d, 64);
            if (lane >= d) bx += t;
        }
        if (lane == (int)blockIdx.x) s_off = bx - bv;
    }
    __syncthreads();
    const int off = s_off;

    if (i < NN) {
        int r = off + excl;
        rowptr[i] = r;
        cursor[i] = r;
        dis[i] = rsqrtf((float)(deg + 1));
        if (i == NN - 1) rowptr[NN] = off + incl;    // grand total
    } else if (i < NNP) {
        dis[i] = 0.f;                                // pad rows (incl. sentinel NN)
    }
}

__global__ void k_fill(const int* __restrict__ src, const int* __restrict__ dst,
                       int* __restrict__ cursor, int* __restrict__ csr, int e) {
    int i = blockIdx.x * blockDim.x + threadIdx.x;
    if (i < e) {
        int d = dst[i];
        int p = atomicAdd(&cursor[d], 1);
        csr[p] = src[i];
    }
}

// ---------------- GEMM helpers ----------------

__device__ __forceinline__ void gld_lds16(const void* g, void* l) {
    __builtin_amdgcn_global_load_lds(
        (const __attribute__((address_space(1))) unsigned int*)g,
        (__attribute__((address_space(3))) unsigned int*)l, 16, 0, 0);
}

// LDS chunk swizzle: row r's 16B chunk q stored at slot q ^ ((r>>1)&3), applied
// by swizzling the GLOBAL source (dest linear per global_load_lds) and XORing
// the fragment-read chunk index.

// ---------------- all layers: single-term fp16 GEMM, TRIPLE-buffered counted-vmcnt ---
// C = (A @ B) * disv[row]; A fp16, B [N,K] fp16.
// T4 pipeline: per step {vmcnt(2); s_barrier; issue stage(t+2); ds_read+MFMA}.
// vmcnt(2) BEFORE the barrier: each wave certifies its own stage(t)'s 2 loads landed;
// stage(t+1)'s 2 loads stay in flight ACROSS the barrier. LDS 48KB -> 3 blk/CU.

__global__ __launch_bounds__(512) void k_gemm_f16(
    const half_t* __restrict__ A,
    const half_t* __restrict__ B,  // [N,K]
    const float* __restrict__ disv,
    half_t* __restrict__ C, int N, int K) {
    __shared__ alignas(16) half_t sA[3][128 * 32];
    __shared__ alignas(16) half_t sB[3][128 * 32];

    const int tid = threadIdx.x;
    const int wave = tid >> 6, lane = tid & 63;
    const int quad = lane >> 4, l16 = lane & 15;
    const int bm = blockIdx.y * 128, bn = blockIdx.x * 128;
    const int wm = (wave >> 1) * 32, wn = (wave & 1) * 64;

    f32x4 aH[2][4];
    #pragma unroll
    for (int i = 0; i < 2; ++i)
        #pragma unroll
        for (int j = 0; j < 4; ++j)
            #pragma unroll
            for (int r = 0; r < 4; ++r) aH[i][j][r] = 0.f;

    const int srow = tid >> 2;
    const int schk = ((tid & 3) ^ ((tid >> 3) & 3)) * 16;
    const unsigned ldso = (unsigned)wave * 1024;

    const char* gA0 = (const char*)(A + (size_t)(bm + srow) * K) + schk;
    const char* gB0 = (const char*)(B + (size_t)(bn + srow) * K) + schk;

    const int rsw = (l16 >> 1) & 3;
    const int nsteps = K >> 5;                       // 16

    // prologue: stage tiles 0 and 1 (4 loads in flight)
    gld_lds16(gA0,      (char*)sA        + ldso);
    gld_lds16(gB0,      (char*)sB        + ldso);
    gld_lds16(gA0 + 64, (char*)sA + 8192 + ldso);
    gld_lds16(gB0 + 64, (char*)sB + 8192 + ldso);

    int cur = 0, nx = 2;
    for (int t = 0; t < nsteps - 1; ++t) {
        // own stage(t) done (newest 2 = stage(t+1) may stay in flight), then publish
        asm volatile("s_waitcnt vmcnt(2)" ::: "memory");
        asm volatile("s_barrier" ::: "memory");
        if (t + 2 < nsteps) {
            const size_t kb = (size_t)(t + 2) * 64;
            gld_lds16(gA0 + kb, (char*)sA + nx * 8192 + ldso);
            gld_lds16(gB0 + kb, (char*)sB + nx * 8192 + ldso);
        }
        const half_t* sAc = (const half_t*)((const char*)sA + cur * 8192);
        const half_t* sBc = (const half_t*)((const char*)sB + cur * 8192);
        half8 fa[2], fb[4];
        #pragma unroll
        for (int i = 0; i < 2; ++i)
            fa[i] = *(const half8*)(sAc + (wm + 16 * i + l16) * 32 + (quad ^ rsw) * 8);
        #pragma unroll
        for (int j = 0; j < 4; ++j)
            fb[j] = *(const half8*)(sBc + (wn + 16 * j + l16) * 32 + (quad ^ rsw) * 8);
        #pragma unroll
        for (int i = 0; i < 2; ++i)
            #pragma unroll
            for (int j = 0; j < 4; ++j)
                aH[i][j] = __builtin_amdgcn_mfma_f32_16x16x32_f16(fa[i], fb[j], aH[i][j], 0, 0, 0);
        cur = (cur == 2) ? 0 : cur + 1;
        nx  = (nx  == 2) ? 0 : nx  + 1;
    }
    // final step: drain everything
    asm volatile("s_waitcnt vmcnt(0)" ::: "memory");
    asm volatile("s_barrier" ::: "memory");
    {
        const half_t* sAc = (const half_t*)((const char*)sA + cur * 8192);
        const half_t* sBc = (const half_t*)((const char*)sB + cur * 8192);
        half8 fa[2], fb[4];
        #pragma unroll
        for (int i = 0; i < 2; ++i)
            fa[i] = *(const half8*)(sAc + (wm + 16 * i + l16) * 32 + (quad ^ rsw) * 8);
        #pragma unroll
        for (int j = 0; j < 4; ++j)
            fb[j] = *(const half8*)(sBc + (wn + 16 * j + l16) * 32 + (quad ^ rsw) * 8);
        #pragma unroll
        for (int i = 0; i < 2; ++i)
            #pragma unroll
            for (int j = 0; j < 4; ++j)
                aH[i][j] = __builtin_amdgcn_mfma_f32_16x16x32_f16(fa[i], fb[j], aH[i][j], 0, 0, 0);
    }

    #pragma unroll
    for (int i = 0; i < 2; ++i) {
        const int rowb = bm + wm + 16 * i + quad * 4;
        float d0 = disv[rowb], d1 = disv[rowb + 1], d2 = disv[rowb + 2], d3 = disv[rowb + 3];
        #pragma unroll
        for (int j = 0; j < 4; ++j) {
            int col = bn + wn + 16 * j + l16;
            C[(size_t)(rowb + 0) * N + col] = (half_t)(aH[i][j][0] * d0);
            C[(size_t)(rowb + 1) * N + col] = (half_t)(aH[i][j][1] * d1);
            C[(size_t)(rowb + 2) * N + col] = (half_t)(aH[i][j][2] * d2);
            C[(size_t)(rowb + 3) * N + col] = (half_t)(aH[i][j][3] * d3);
        }
    }
}

// ---------------- aggregation ----------------
// t' rows pre-scaled by dis[src]; out[i] = (sum t'[src] + t'[i])*dis[i] + b.
// CSR padded %8 with sentinel NN (t'[NN]=0 exactly).

// Layers 1-2: fused relu, single fp16 output (next GEMM A). D=512. 2 nodes/block.
__global__ __launch_bounds__(128) void k_agg16(
    const half_t* __restrict__ t, const int* __restrict__ rowptr,
    const int* __restrict__ csr, const float* __restrict__ dis,
    const float* __restrict__ bias, half_t* __restrict__ out) {
    const int node = blockIdx.x * 2 + (threadIdx.x >> 6);
    const int lane = threadIdx.x & 63;  // 64 lanes x 8 elems (16B loads)
    const int beg = rowptr[node], end = rowptr[node + 1];
    const float din = dis[node];
    const char* tc = (const char*)t;
    const unsigned lb = (unsigned)lane * 16u;

    float a0[8], a1[8], a2[8], a3[8];
    #pragma unroll
    for (int c = 0; c < 8; ++c) { a0[c] = 0.f; a1[c] = 0.f; a2[c] = 0.f; a3[c] = 0.f; }

    if (beg < end) {
        int4 sa = *(const int4*)(csr + beg);
        int4 sb = *(const int4*)(csr + beg + 4);
        half8 v0 = *(const half8*)(tc + (((unsigned)sa.x) << 10) + lb);
        half8 v1 = *(const half8*)(tc + (((unsigned)sa.y) << 10) + lb);
        half8 v2 = *(const half8*)(tc + (((unsigned)sa.z) << 10) + lb);
        half8 v3 = *(const half8*)(tc + (((unsigned)sa.w) << 10) + lb);
        half8 v4 = *(const half8*)(tc + (((unsigned)sb.x) << 10) + lb);
        half8 v5 = *(const half8*)(tc + (((unsigned)sb.y) << 10) + lb);
        half8 v6 = *(const half8*)(tc + (((unsigned)sb.z) << 10) + lb);
        half8 v7 = *(const half8*)(tc + (((unsigned)sb.w) << 10) + lb);
        int4 na = sa, nb = sb;
        if (beg + 8 < end) {
            na = *(const int4*)(csr + beg + 8);
            nb = *(const int4*)(csr + beg + 12);
        }
        for (int e = beg; e < end; ) {
            half8 u0 = v0, u1 = v1, u2 = v2, u3 = v3, u4 = v4, u5 = v5, u6 = v6, u7 = v7;
            e += 8;
            if (e < end) {
                v0 = *(const half8*)(tc + (((unsigned)na.x) << 10) + lb);
                v1 = *(const half8*)(tc + (((unsigned)na.y) << 10) + lb);
                v2 = *(const half8*)(tc + (((unsigned)na.z) << 10) + lb);
                v3 = *(const half8*)(tc + (((unsigned)na.w) << 10) + lb);
                v4 = *(const half8*)(tc + (((unsigned)nb.x) << 10) + lb);
                v5 = *(const half8*)(tc + (((unsigned)nb.y) << 10) + lb);
                v6 = *(const half8*)(tc + (((unsigned)nb.z) << 10) + lb);
                v7 = *(const half8*)(tc + (((unsigned)nb.w) << 10) + lb);
                if (e + 8 < end) {
                    na = *(const int4*)(csr + e + 8);
                    nb = *(const int4*)(csr + e + 12);
                }
            }
            #pragma unroll
            for (int c = 0; c < 8; ++c) {
                a0[c] = fmaf((float)u0[c], din, a0[c]);
                a1[c] = fmaf((float)u1[c], din, a1[c]);
                a2[c] = fmaf((float)u2[c], din, a2[c]);
                a3[c] = fmaf((float)u3[c], din, a3[c]);
                a0[c] = fmaf((float)u4[c], din, a0[c]);
                a1[c] = fmaf((float)u5[c], din, a1[c]);
                a2[c] = fmaf((float)u6[c], din, a2[c]);
                a3[c] = fmaf((float)u7[c], din, a3[c]);
            }
        }
    }

    half8 sv = ((const half8*)(t + (size_t)node * DH))[lane];
    f32x4 bv0 = ((const f32x4*)bias)[lane * 2];
    f32x4 bv1 = ((const f32x4*)bias)[lane * 2 + 1];
    half8 h;
    #pragma unroll
    for (int c = 0; c < 8; ++c) {
        float b = (c < 4) ? bv0[c] : bv1[c - 4];
        float acc = (a0[c] + a1[c]) + (a2[c] + a3[c]);
        float o = fmaf((float)sv[c], din, acc) + b;
        o = fmaxf(o, 0.f);
        h[c] = (half_t)o;
    }
    __builtin_nontemporal_store(h, (half8*)(out + (size_t)node * DH + lane * 8));
}

// Layer 3: fp32 emb only (heads split in-register), no relu. D=256. 4 nodes/block.
__global__ __launch_bounds__(128) void k_agg_f32(
    const half_t* __restrict__ t, const int* __restrict__ rowptr,
    const int* __restrict__ csr, const float* __restrict__ dis,
    const float* __restrict__ bias, float* __restrict__ out) {
    const int node = blockIdx.x * 4 + (threadIdx.x >> 5);
    const int lane = threadIdx.x & 31;  // 32 lanes x 8 elems (16B loads)
    const int beg = rowptr[node], end = rowptr[node + 1];
    const float din = dis[node];
    const char* tc = (const char*)t;
    const unsigned lb = (unsigned)lane * 16u;

    float a0[8], a1[8], a2[8], a3[8];
    #pragma unroll
    for (int c = 0; c < 8; ++c) { a0[c] = 0.f; a1[c] = 0.f; a2[c] = 0.f; a3[c] = 0.f; }

    if (beg < end) {
        int4 sa = *(const int4*)(csr + beg);
        int4 sb = *(const int4*)(csr + beg + 4);
        half8 v0 = *(const half8*)(tc + (((unsigned)sa.x) << 9) + lb);
        half8 v1 = *(const half8*)(tc + (((unsigned)sa.y) << 9) + lb);
        half8 v2 = *(const half8*)(tc + (((unsigned)sa.z) << 9) + lb);
        half8 v3 = *(const half8*)(tc + (((unsigned)sa.w) << 9) + lb);
        half8 v4 = *(const half8*)(tc + (((unsigned)sb.x) << 9) + lb);
        half8 v5 = *(const half8*)(tc + (((unsigned)sb.y) << 9) + lb);
        half8 v6 = *(const half8*)(tc + (((unsigned)sb.z) << 9) + lb);
        half8 v7 = *(const half8*)(tc + (((unsigned)sb.w) << 9) + lb);
        int4 na = sa, nb = sb;
        if (beg + 8 < end) {
            na = *(const int4*)(csr + beg + 8);
            nb = *(const int4*)(csr + beg + 12);
        }
        for (int e = beg; e < end; ) {
            half8 u0 = v0, u1 = v1, u2 = v2, u3 = v3, u4 = v4, u5 = v5, u6 = v6, u7 = v7;
            e += 8;
            if (e < end) {
                v0 = *(const half8*)(tc + (((unsigned)na.x) << 9) + lb);
                v1 = *(const half8*)(tc + (((unsigned)na.y) << 9) + lb);
                v2 = *(const half8*)(tc + (((unsigned)na.z) << 9) + lb);
                v3 = *(const half8*)(tc + (((unsigned)na.w) << 9) + lb);
                v4 = *(const half8*)(tc + (((unsigned)nb.x) << 9) + lb);
                v5 = *(const half8*)(tc + (((unsigned)nb.y) << 9) + lb);
                v6 = *(const half8*)(tc + (((unsigned)nb.z) << 9) + lb);
                v7 = *(const half8*)(tc + (((unsigned)nb.w) << 9) + lb);
                if (e + 8 < end) {
                    na = *(const int4*)(csr + e + 8);
                    nb = *(const int4*)(csr + e + 12);
                }
            }
            #pragma unroll
            for (int c = 0; c < 8; ++c) {
                a0[c] = fmaf((float)u0[c], din, a0[c]);
                a1[c] = fmaf((float)u1[c], din, a1[c]);
                a2[c] = fmaf((float)u2[c], din, a2[c]);
                a3[c] = fmaf((float)u3[c], din, a3[c]);
                a0[c] = fmaf((float)u4[c], din, a0[c]);
                a1[c] = fmaf((float)u5[c], din, a1[c]);
                a2[c] = fmaf((float)u6[c], din, a2[c]);
                a3[c] = fmaf((float)u7[c], din, a3[c]);
            }
        }
    }

    half8 sv = ((const half8*)(t + (size_t)node * DE))[lane];
    f32x4 bv0 = ((const f32x4*)bias)[lane * 2];
    f32x4 bv1 = ((const f32x4*)bias)[lane * 2 + 1];
    f32x4 o0, o1;
    #pragma unroll
    for (int c = 0; c < 8; ++c) {
        float b = (c < 4) ? bv0[c] : bv1[c - 4];
        float acc = (a0[c] + a1[c]) + (a2[c] + a3[c]);
        float o = fmaf((float)sv[c], din, acc) + b;
        if (c < 4) o0[c] = o; else o1[c - 4] = o;
    }
    ((f32x4*)(out + (size_t)node * DE))[lane * 2]     = o0;
    ((f32x4*)(out + (size_t)node * DE))[lane * 2 + 1] = o1;
}

// ---------------- MFMA heads: emb fp32 -> in-register bf16 hi/lo split -> MFMA ----------

__global__ __launch_bounds__(256) void k_heads_mfma(
    const float* __restrict__ emb,
    const bf16_t* __restrict__ Wth, const bf16_t* __restrict__ Wtl,
    const float* __restrict__ bc,
    float* __restrict__ oe, float* __restrict__ oh, float* __restrict__ og) {
    const int wave = threadIdx.x >> 6, lane = threadIdx.x & 63;
    const int quad = lane >> 4, l16 = lane & 15;
    const int row0 = blockIdx.x * 64 + wave * 16;

    f32x4 acc[5];
    #pragma unroll
    for (int j = 0; j < 5; ++j)
        #pragma unroll
        for (int r = 0; r < 4; ++r) acc[j][r] = 0.f;

    const int arow = row0 + l16;
    const size_t abase = (size_t)((arow < NN) ? arow : 0) * 256 + quad * 8;  // clamp pad rows
    #pragma unroll
    for (int ks = 0; ks < 256; ks += 32) {
        f32x4 e0 = *(const f32x4*)(emb + abase + ks);
        f32x4 e1 = *(const f32x4*)(emb + abase + ks + 4);
        bf16x8 ah, al;
        #pragma unroll
        for (int c = 0; c < 4; ++c) {
            float f = e0[c];
            bf16_t h = (bf16_t)f;
            ah[c] = h;
            al[c] = (bf16_t)(f - (float)h);
            float g = e1[c];
            bf16_t h2 = (bf16_t)g;
            ah[4 + c] = h2;
            al[4 + c] = (bf16_t)(g - (float)h2);
        }
        #pragma unroll
        for (int j = 0; j < 5; ++j) {
            const size_t bbase = (size_t)(j * 16 + l16) * 256 + ks + quad * 8;
            bf16x8 bh = *(const bf16x8*)(Wth + bbase);
            bf16x8 bl = *(const bf16x8*)(Wtl + bbase);
            acc[j] = __builtin_amdgcn_mfma_f32_16x16x32_bf16(ah, bh, acc[j], 0, 0, 0);
            acc[j] = __builtin_amdgcn_mfma_f32_16x16x32_bf16(ah, bl, acc[j], 0, 0, 0);
            acc[j] = __builtin_amdgcn_mfma_f32_16x16x32_bf16(al, bh, acc[j], 0, 0, 0);
        }
    }

    #pragma unroll
    for (int j = 0; j < 5; ++j) {
        int col = j * 16 + l16;
        if (col < 72) {
            float b = bc[col];
            #pragma unroll
            for (int r = 0; r < 4; ++r) {
                int row = row0 + quad * 4 + r;
                if (row < NN) {
                    float v = acc[j][r] + b;
                    if (col < 7)       oe[(size_t)row * 7 + col] = v;
                    else if (col < 15) oh[(size_t)row * 8 + (col - 7)] = v;
                    else               og[(size_t)row * 57 + (col - 15)] = v;
                }
            }
        }
    }
}

// ---------------- launch ----------------

extern "C" void kernel_launch(void* const* d_in, const int* in_sizes, int n_in,
                              void* d_out, int out_size, void* d_ws, size_t ws_size,
                              hipStream_t stream) {
    const float* x   = (const float*)d_in[0];
    const int*   ei  = (const int*)d_in[1];
    const float* W1  = (const float*)d_in[2];
    const float* b1  = (const float*)d_in[3];
    const float* W2  = (const float*)d_in[4];
    const float* b2  = (const float*)d_in[5];
    const float* W3  = (const float*)d_in[6];
    const float* b3  = (const float*)d_in[7];
    const float* We  = (const float*)d_in[8];
    const float* be  = (const float*)d_in[9];
    const float* Wh  = (const float*)d_in[10];
    const float* bh  = (const float*)d_in[11];
    const float* Wg  = (const float*)d_in[12];
    const float* bg  = (const float*)d_in[13];

    const int* e_src = ei;
    const int* e_dst = ei + NE;

    // workspace layout (~110 MB):
    //   buf0: GEMM outputs t' (fp16 NNP x 512)
    //   buf1: Xf16 (prep), then agg outputs / next GEMM A (fp16) -- X dead after GEMM1
    half_t* buf0 = (half_t*)d_ws;
    half_t* buf1 = buf0 + (size_t)NNP * DH;
    half_t* B1h  = buf1 + (size_t)NNP * DH;             // [512,512] f16
    half_t* B2h  = B1h + (size_t)DIN * DH;
    half_t* B3h  = B2h + (size_t)DH * DH;               // [256,512] f16
    bf16_t* Wth  = (bf16_t*)(B3h + (size_t)DE * DH);
    bf16_t* Wtl  = Wth + 80 * 256;
    float*  bc   = (float*)(Wtl + 80 * 256);            // 80 fp32 (pad 128)
    int*   indeg  = (int*)(bc + 128);
    int*   rowptr = indeg + 50048;                      // 50001 used
    int*   cursor = rowptr + 50048;
    float* dis    = (float*)(cursor + 50048);           // NNP floats (pad+sentinel = 0)
    int*   csr    = (int*)(dis + 50048);                // CSR_CAP
    int*   bsum   = csr + CSR_CAP;                      // 64
    int*   done   = bsum + 64;                          // 1 (scan barrier counter)

    float* emb   = (float*)d_out;                       // 50000*256
    float* out_e = emb + (size_t)NN * DE;               // 50000*7
    float* out_h = out_e + (size_t)NN * 7;              // 50000*8
    float* out_g = out_h + (size_t)NN * 8;              // 50000*57

    // 1) prep: zero indeg, then all input-only transforms in one wide launch
    hipMemsetAsync(indeg, 0, NN * sizeof(int), stream);
    k_prep<<<PB_TOTAL, 256, 0, stream>>>(x, buf1, e_dst, indeg, csr,
                                         W1, B1h, W2, B2h, W3, B3h,
                                         We, be, Wh, bh, Wg, bg, Wth, Wtl, bc, done);
    // 2) single-kernel scan + CSR fill
    k_scan<<<SCAN_BLOCKS, 1024, 0, stream>>>(indeg, rowptr, cursor, dis, bsum, done);
    k_fill<<<(NE + 255) / 256, 256, 0, stream>>>(e_src, e_dst, cursor, csr, NE);

    const int gy = NNP / 128;  // 391

    // 3) layer 1: fp16 single-term GEMM (X fp16), dis-scaled fp16 out
    k_gemm_f16<<<dim3(DH / 128, gy), 512, 0, stream>>>(buf1, B1h, dis, buf0, DH, DIN);
    k_agg16<<<NN / 2, 128, 0, stream>>>(buf0, rowptr, csr, dis, b1, buf1);

    // 4) layer 2: fp16 single-term GEMM, dis-scaled fp16 out
    k_gemm_f16<<<dim3(DH / 128, gy), 512, 0, stream>>>(buf1, B2h, dis, buf0, DH, DH);
    k_agg16<<<NN / 2, 128, 0, stream>>>(buf0, rowptr, csr, dis, b2, buf1);

    // 5) layer 3: fp16 single-term GEMM -> t3' (NNP x 256), then agg -> fp32 emb
    k_gemm_f16<<<dim3(DE / 128, gy), 512, 0, stream>>>(buf1, B3h, dis, buf0, DE, DH);
    k_agg_f32<<<NN / 4, 128, 0, stream>>>(buf0, rowptr, csr, dis, b3, emb);

    // 6) heads via MFMA (reads fp32 emb, splits in-register)
    k_heads_mfma<<<NNP / 64, 256, 0, stream>>>(emb, Wth, Wtl, bc, out_e, out_h, out_g);
}

// Round 11
// 724.339 us; speedup vs baseline: 1.1627x; 1.0307x over previous
//
#include <hip/hip_runtime.h>

// Problem constants (fixed by reference)
#define NN   50000
#define NNP  50048   // padded to 391*128
#define NE   800000
#define DIN  512
#define DH   512
#define DE   256

// CSR padded to multiple of 8 per node, sentinel = NN (dis[NN]=0, t'[NN]=0 row)
#define CSR_CAP 1150016  // >= NE + 7*NN, multiple of 16 ints

typedef __bf16 bf16_t;
typedef __bf16 bf16x8 __attribute__((ext_vector_type(8)));
typedef float  f32x4  __attribute__((ext_vector_type(4)));
typedef _Float16 half_t;
typedef _Float16 half4 __attribute__((ext_vector_type(4)));
typedef _Float16 half8 __attribute__((ext_vector_type(8)));

// ---------------- fused prep kernel ----------------
//   (a) X fp32 -> X fp16 (single stream)
//   (b) indegree atomics
//   (c) csr sentinel prefill
//   (d,e,f) W1/W2/W3 -> fp16 transpose (single stream)
//   (g) combined head weights + bias (bf16 hi/lo, full precision for fp32 outputs)
#define PB_SPLIT 25024   // NNP*DIN/4/256 exactly
#define PB_IDEG  3125    // NE/256 exactly
#define PB_CSR   1124    // ceil(CSR_CAP/4/256)
#define PB_W1    1024    // 512*512/256
#define PB_W2    1024
#define PB_W3    512     // 512*256/256
#define PB_HEADW 80      // 80*256/256
#define PB_TOTAL (PB_SPLIT + PB_IDEG + PB_CSR + PB_W1 + PB_W2 + PB_W3 + PB_HEADW)

__global__ void k_prep(const float* __restrict__ X, half_t* __restrict__ Xf,
                       const int* __restrict__ dst,
                       int* __restrict__ indeg, int* __restrict__ csr,
                       const float* __restrict__ W1, half_t* __restrict__ B1h,
                       const float* __restrict__ W2, half_t* __restrict__ B2h,
                       const float* __restrict__ W3, half_t* __restrict__ B3h,
                       const float* __restrict__ We, const float* __restrict__ be,
                       const float* __restrict__ Wh, const float* __restrict__ bh,
                       const float* __restrict__ Wg, const float* __restrict__ bg,
                       bf16_t* __restrict__ Wth, bf16_t* __restrict__ Wtl,
                       float* __restrict__ bc, int* __restrict__ done) {
    int b = blockIdx.x;
    if (b < PB_SPLIT) {
        long idx = (long)b * 256 + threadIdx.x;      // < NNP*DIN/4
        long base = idx * 4;
        int row = (int)(base >> 9);                  // /DIN
        f32x4 v;
        if (row < NN) v = *(const f32x4*)(X + base);
        else { v[0] = 0.f; v[1] = 0.f; v[2] = 0.f; v[3] = 0.f; }
        half4 h;
        #pragma unroll
        for (int c = 0; c < 4; ++c) h[c] = (half_t)v[c];
        *(half4*)(Xf + base) = h;
        return;
    }
    b -= PB_SPLIT;
    if (b < PB_IDEG) {
        int i = b * 256 + threadIdx.x;               // NE exact
        atomicAdd(&indeg[dst[i]], 1);
        return;
    }
    b -= PB_IDEG;
    if (b < PB_CSR) {
        int i = b * 256 + threadIdx.x;
        if (i < CSR_CAP / 4) ((int4*)csr)[i] = make_int4(NN, NN, NN, NN);
        return;
    }
    b -= PB_CSR;
    if (b < PB_W1) {
        int idx = b * 256 + threadIdx.x;             // 512x512 exact
        int k = idx >> 9, n = idx & 511;
        B1h[(size_t)n * DIN + k] = (half_t)W1[idx];
        return;
    }
    b -= PB_W1;
    if (b < PB_W2) {
        int idx = b * 256 + threadIdx.x;             // 512x512 exact
        int k = idx >> 9, n = idx & 511;
        B2h[(size_t)n * DH + k] = (half_t)W2[idx];
        return;
    }
    b -= PB_W2;
    if (b < PB_W3) {
        int idx = b * 256 + threadIdx.x;             // 512x256 exact, W3[k][n]
        int k = idx >> 8, n = idx & 255;
        B3h[(size_t)n * DH + k] = (half_t)W3[idx];
        return;
    }
    b -= PB_W3;
    {
        int idx = b * 256 + threadIdx.x;             // 80*256 exact
        int n = idx / 256, k = idx % 256;
        if (idx == 0) *done = 0;                     // reset scan barrier counter
        float f = 0.f;
        if (n < 7)       f = We[k * 7 + n];
        else if (n < 15) f = Wh[k * 8 + (n - 7)];
        else if (n < 72) f = Wg[k * 57 + (n - 15)];
        bf16_t h = (bf16_t)f;
        Wth[idx] = h;
        Wtl[idx] = (bf16_t)(f - (float)h);
        if (k == 0) {
            float bb = 0.f;
            if (n < 7)       bb = be[n];
            else if (n < 15) bb = bh[n - 7];
            else if (n < 72) bb = bg[n - 15];
            bc[n] = bb;
        }
    }
}

// ---------------- single-kernel parallel scan (49 all-resident blocks) ----------------
#define SCAN_BLOCKS 49   // ceil(NN/1024); 49 blocks <= 256 CUs -> all resident, spin safe

__global__ __launch_bounds__(1024) void k_scan(const int* __restrict__ indeg,
                                               int* __restrict__ rowptr,
                                               int* __restrict__ cursor,
                                               float* __restrict__ dis,
                                               int* __restrict__ bsum,
                                               int* __restrict__ done) {
    __shared__ int wsum[16];
    __shared__ int s_off;
    const int tid = threadIdx.x, lane = tid & 63, wid = tid >> 6;
    const int i = blockIdx.x * 1024 + tid;
    int deg = (i < NN) ? indeg[i] : 0;
    int v = (deg + 7) & ~7;                          // pad segment to %8
    int x = v;
    #pragma unroll
    for (int d = 1; d < 64; d <<= 1) {
        int t = __shfl_up(x, d, 64);
        if (lane >= d) x += t;
    }
    if (lane == 63) wsum[wid] = x;
    __syncthreads();
    if (wid == 0) {
        int s = (lane < 16) ? wsum[lane] : 0;
        #pragma unroll
        for (int d = 1; d < 16; d <<= 1) {
            int t = __shfl_up(s, d, 64);
            if (lane >= d) s += t;
        }
        if (lane < 16) wsum[lane] = s;               // inclusive wave prefix
    }
    __syncthreads();
    int woff = (wid > 0) ? wsum[wid - 1] : 0;
    int incl = x + woff;                             // inclusive prefix within block
    int excl = incl - v;

    // post block total, barrier on all 49 blocks
    if (tid == 0) {
        bsum[blockIdx.x] = wsum[15];
        __threadfence();
        atomicAdd(done, 1);
        while (atomicAdd(done, 0) < SCAN_BLOCKS) { }
        __threadfence();
    }
    __syncthreads();

    // per-block exclusive offset from bsum
    if (wid == 0) {
        int bv = (lane < SCAN_BLOCKS) ? bsum[lane] : 0;
        int bx = bv;
        #pragma unroll
        for (int d = 1; d < 64; d <<= 1) {
            int t = __shfl_up(bx, d, 64);
            if (lane >= d) bx += t;
        }
        if (lane == (int)blockIdx.x) s_off = bx - bv;
    }
    __syncthreads();
    const int off = s_off;

    if (i < NN) {
        int r = off + excl;
        rowptr[i] = r;
        cursor[i] = r;
        dis[i] = rsqrtf((float)(deg + 1));
        if (i == NN - 1) rowptr[NN] = off + incl;    // grand total
    } else if (i < NNP) {
        dis[i] = 0.f;                                // pad rows (incl. sentinel NN)
    }
}

__global__ void k_fill(const int* __restrict__ src, const int* __restrict__ dst,
                       int* __restrict__ cursor, int* __restrict__ csr, int e) {
    int i = blockIdx.x * blockDim.x + threadIdx.x;
    if (i < e) {
        int d = dst[i];
        int p = atomicAdd(&cursor[d], 1);
        csr[p] = src[i];
    }
}

// ---------------- GEMM helpers ----------------

__device__ __forceinline__ void gld_lds16(const void* g, void* l) {
    __builtin_amdgcn_global_load_lds(
        (const __attribute__((address_space(1))) unsigned int*)g,
        (__attribute__((address_space(3))) unsigned int*)l, 16, 0, 0);
}

// LDS chunk swizzle: row r's 16B chunk q stored at slot q ^ ((r>>1)&3), applied
// by swizzling the GLOBAL source (dest linear per global_load_lds) and XORing
// the fragment-read chunk index. Note the B half-tile offset (128 rows) is a
// multiple of 4 so both halves share the same swizzle phase.

// ---------------- all layers: single-term fp16 GEMM, 128x256 tile, 3-buf vmcnt ------
// C = (A @ B) * disv[row]; A fp16 [M,K], B [N,K] fp16. BM=128, BN=256, BK=32.
// 8 waves; wave covers 32x128 -> 16 MFMA/phase (2x the old 128x128 tile, halving
// sync overhead per FLOP — the GEMMs are MFMA-issue-bound, not BW-bound).
// T4 pipeline: per step {vmcnt(3); s_barrier; issue stage(t+2) [3 loads]; ds_read+MFMA}.
// LDS = 3 x (8KB A + 16KB B) = 72 KB -> 2 blocks/CU.

__global__ __launch_bounds__(512) void k_gemm_f16(
    const half_t* __restrict__ A,
    const half_t* __restrict__ B,  // [N,K]
    const float* __restrict__ disv,
    half_t* __restrict__ C, int N, int K) {
    __shared__ alignas(16) half_t sA[3 * 128 * 32];   // 3 x 8 KB
    __shared__ alignas(16) half_t sB[3 * 256 * 32];   // 3 x 16 KB

    const int tid = threadIdx.x;
    const int wave = tid >> 6, lane = tid & 63;
    const int quad = lane >> 4, l16 = lane & 15;
    const int bm = blockIdx.y * 128, bn = blockIdx.x * 256;
    const int wm = (wave >> 1) * 32, wn = (wave & 1) * 128;

    f32x4 aH[2][8];
    #pragma unroll
    for (int i = 0; i < 2; ++i)
        #pragma unroll
        for (int j = 0; j < 8; ++j)
            #pragma unroll
            for (int r = 0; r < 4; ++r) aH[i][j][r] = 0.f;

    const int srow = tid >> 2;                        // 0..127
    const int schk = ((tid & 3) ^ ((tid >> 3) & 3)) * 16;
    const unsigned ldso = (unsigned)wave * 1024;

    const char* gA0 = (const char*)(A + (size_t)(bm + srow) * K) + schk;
    const char* gB0 = (const char*)(B + (size_t)(bn + srow) * K) + schk;
    const size_t bstep = (size_t)128 * K * 2;         // B rows 128..255 (same swizzle phase)

    const int rsw = (l16 >> 1) & 3;
    const int nsteps = K >> 5;                        // 16 or 8

    // prologue: stage tiles 0 and 1 (6 loads in flight)
    gld_lds16(gA0,          (char*)sA         + ldso);
    gld_lds16(gB0,          (char*)sB         + ldso);
    gld_lds16(gB0 + bstep,  (char*)sB +  8192 + ldso);
    gld_lds16(gA0 + 64,     (char*)sA +  8192 + ldso);
    gld_lds16(gB0 + 64,         (char*)sB + 16384 + ldso);
    gld_lds16(gB0 + 64 + bstep, (char*)sB + 24576 + ldso);

    int cur = 0, nx = 2;
    for (int t = 0; t < nsteps - 1; ++t) {
        // own stage(t)'s 3 loads done (stage(t+1)'s 3 may stay in flight), publish
        asm volatile("s_waitcnt vmcnt(3)" ::: "memory");
        asm volatile("s_barrier" ::: "memory");
        if (t + 2 < nsteps) {
            const size_t kb = (size_t)(t + 2) * 64;
            gld_lds16(gA0 + kb,         (char*)sA + nx * 8192  + ldso);
            gld_lds16(gB0 + kb,         (char*)sB + nx * 16384 + ldso);
            gld_lds16(gB0 + kb + bstep, (char*)sB + nx * 16384 + 8192 + ldso);
        }
        const half_t* sAc = (const half_t*)((const char*)sA + cur * 8192);
        const half_t* sBc = (const half_t*)((const char*)sB + cur * 16384);
        half8 fa[2], fb[8];
        #pragma unroll
        for (int i = 0; i < 2; ++i)
            fa[i] = *(const half8*)(sAc + (wm + 16 * i + l16) * 32 + (quad ^ rsw) * 8);
        #pragma unroll
        for (int j = 0; j < 8; ++j)
            fb[j] = *(const half8*)(sBc + (wn + 16 * j + l16) * 32 + (quad ^ rsw) * 8);
        #pragma unroll
        for (int i = 0; i < 2; ++i)
            #pragma unroll
            for (int j = 0; j < 8; ++j)
                aH[i][j] = __builtin_amdgcn_mfma_f32_16x16x32_f16(fa[i], fb[j], aH[i][j], 0, 0, 0);
        cur = (cur == 2) ? 0 : cur + 1;
        nx  = (nx  == 2) ? 0 : nx  + 1;
    }
    // final step: drain everything
    asm volatile("s_waitcnt vmcnt(0)" ::: "memory");
    asm volatile("s_barrier" ::: "memory");
    {
        const half_t* sAc = (const half_t*)((const char*)sA + cur * 8192);
        const half_t* sBc = (const half_t*)((const char*)sB + cur * 16384);
        half8 fa[2], fb[8];
        #pragma unroll
        for (int i = 0; i < 2; ++i)
            fa[i] = *(const half8*)(sAc + (wm + 16 * i + l16) * 32 + (quad ^ rsw) * 8);
        #pragma unroll
        for (int j = 0; j < 8; ++j)
            fb[j] = *(const half8*)(sBc + (wn + 16 * j + l16) * 32 + (quad ^ rsw) * 8);
        #pragma unroll
        for (int i = 0; i < 2; ++i)
            #pragma unroll
            for (int j = 0; j < 8; ++j)
                aH[i][j] = __builtin_amdgcn_mfma_f32_16x16x32_f16(fa[i], fb[j], aH[i][j], 0, 0, 0);
    }

    #pragma unroll
    for (int i = 0; i < 2; ++i) {
        const int rowb = bm + wm + 16 * i + quad * 4;
        float d0 = disv[rowb], d1 = disv[rowb + 1], d2 = disv[rowb + 2], d3 = disv[rowb + 3];
        #pragma unroll
        for (int j = 0; j < 8; ++j) {
            int col = bn + wn + 16 * j + l16;
            C[(size_t)(rowb + 0) * N + col] = (half_t)(aH[i][j][0] * d0);
            C[(size_t)(rowb + 1) * N + col] = (half_t)(aH[i][j][1] * d1);
            C[(size_t)(rowb + 2) * N + col] = (half_t)(aH[i][j][2] * d2);
            C[(size_t)(rowb + 3) * N + col] = (half_t)(aH[i][j][3] * d3);
        }
    }
}

// ---------------- aggregation ----------------
// t' rows pre-scaled by dis[src]; out[i] = (sum t'[src] + t'[i])*dis[i] + b.
// CSR padded %8 with sentinel NN (t'[NN]=0 exactly).

// Layers 1-2: fused relu, single fp16 output (next GEMM A). D=512. 2 nodes/block.
__global__ __launch_bounds__(128) void k_agg16(
    const half_t* __restrict__ t, const int* __restrict__ rowptr,
    const int* __restrict__ csr, const float* __restrict__ dis,
    const float* __restrict__ bias, half_t* __restrict__ out) {
    const int node = blockIdx.x * 2 + (threadIdx.x >> 6);
    const int lane = threadIdx.x & 63;  // 64 lanes x 8 elems (16B loads)
    const int beg = rowptr[node], end = rowptr[node + 1];
    const float din = dis[node];
    const char* tc = (const char*)t;
    const unsigned lb = (unsigned)lane * 16u;

    float a0[8], a1[8], a2[8], a3[8];
    #pragma unroll
    for (int c = 0; c < 8; ++c) { a0[c] = 0.f; a1[c] = 0.f; a2[c] = 0.f; a3[c] = 0.f; }

    if (beg < end) {
        int4 sa = *(const int4*)(csr + beg);
        int4 sb = *(const int4*)(csr + beg + 4);
        half8 v0 = *(const half8*)(tc + (((unsigned)sa.x) << 10) + lb);
        half8 v1 = *(const half8*)(tc + (((unsigned)sa.y) << 10) + lb);
        half8 v2 = *(const half8*)(tc + (((unsigned)sa.z) << 10) + lb);
        half8 v3 = *(const half8*)(tc + (((unsigned)sa.w) << 10) + lb);
        half8 v4 = *(const half8*)(tc + (((unsigned)sb.x) << 10) + lb);
        half8 v5 = *(const half8*)(tc + (((unsigned)sb.y) << 10) + lb);
        half8 v6 = *(const half8*)(tc + (((unsigned)sb.z) << 10) + lb);
        half8 v7 = *(const half8*)(tc + (((unsigned)sb.w) << 10) + lb);
        int4 na = sa, nb = sb;
        if (beg + 8 < end) {
            na = *(const int4*)(csr + beg + 8);
            nb = *(const int4*)(csr + beg + 12);
        }
        for (int e = beg; e < end; ) {
            half8 u0 = v0, u1 = v1, u2 = v2, u3 = v3, u4 = v4, u5 = v5, u6 = v6, u7 = v7;
            e += 8;
            if (e < end) {
                v0 = *(const half8*)(tc + (((unsigned)na.x) << 10) + lb);
                v1 = *(const half8*)(tc + (((unsigned)na.y) << 10) + lb);
                v2 = *(const half8*)(tc + (((unsigned)na.z) << 10) + lb);
                v3 = *(const half8*)(tc + (((unsigned)na.w) << 10) + lb);
                v4 = *(const half8*)(tc + (((unsigned)nb.x) << 10) + lb);
                v5 = *(const half8*)(tc + (((unsigned)nb.y) << 10) + lb);
                v6 = *(const half8*)(tc + (((unsigned)nb.z) << 10) + lb);
                v7 = *(const half8*)(tc + (((unsigned)nb.w) << 10) + lb);
                if (e + 8 < end) {
                    na = *(const int4*)(csr + e + 8);
                    nb = *(const int4*)(csr + e + 12);
                }
            }
            #pragma unroll
            for (int c = 0; c < 8; ++c) {
                a0[c] = fmaf((float)u0[c], din, a0[c]);
                a1[c] = fmaf((float)u1[c], din, a1[c]);
                a2[c] = fmaf((float)u2[c], din, a2[c]);
                a3[c] = fmaf((float)u3[c], din, a3[c]);
                a0[c] = fmaf((float)u4[c], din, a0[c]);
                a1[c] = fmaf((float)u5[c], din, a1[c]);
                a2[c] = fmaf((float)u6[c], din, a2[c]);
                a3[c] = fmaf((float)u7[c], din, a3[c]);
            }
        }
    }

    half8 sv = ((const half8*)(t + (size_t)node * DH))[lane];
    f32x4 bv0 = ((const f32x4*)bias)[lane * 2];
    f32x4 bv1 = ((const f32x4*)bias)[lane * 2 + 1];
    half8 h;
    #pragma unroll
    for (int c = 0; c < 8; ++c) {
        float b = (c < 4) ? bv0[c] : bv1[c - 4];
        float acc = (a0[c] + a1[c]) + (a2[c] + a3[c]);
        float o = fmaf((float)sv[c], din, acc) + b;
        o = fmaxf(o, 0.f);
        h[c] = (half_t)o;
    }
    __builtin_nontemporal_store(h, (half8*)(out + (size_t)node * DH + lane * 8));
}

// Layer 3: fp32 emb only (heads split in-register), no relu. D=256. 4 nodes/block.
__global__ __launch_bounds__(128) void k_agg_f32(
    const half_t* __restrict__ t, const int* __restrict__ rowptr,
    const int* __restrict__ csr, const float* __restrict__ dis,
    const float* __restrict__ bias, float* __restrict__ out) {
    const int node = blockIdx.x * 4 + (threadIdx.x >> 5);
    const int lane = threadIdx.x & 31;  // 32 lanes x 8 elems (16B loads)
    const int beg = rowptr[node], end = rowptr[node + 1];
    const float din = dis[node];
    const char* tc = (const char*)t;
    const unsigned lb = (unsigned)lane * 16u;

    float a0[8], a1[8], a2[8], a3[8];
    #pragma unroll
    for (int c = 0; c < 8; ++c) { a0[c] = 0.f; a1[c] = 0.f; a2[c] = 0.f; a3[c] = 0.f; }

    if (beg < end) {
        int4 sa = *(const int4*)(csr + beg);
        int4 sb = *(const int4*)(csr + beg + 4);
        half8 v0 = *(const half8*)(tc + (((unsigned)sa.x) << 9) + lb);
        half8 v1 = *(const half8*)(tc + (((unsigned)sa.y) << 9) + lb);
        half8 v2 = *(const half8*)(tc + (((unsigned)sa.z) << 9) + lb);
        half8 v3 = *(const half8*)(tc + (((unsigned)sa.w) << 9) + lb);
        half8 v4 = *(const half8*)(tc + (((unsigned)sb.x) << 9) + lb);
        half8 v5 = *(const half8*)(tc + (((unsigned)sb.y) << 9) + lb);
        half8 v6 = *(const half8*)(tc + (((unsigned)sb.z) << 9) + lb);
        half8 v7 = *(const half8*)(tc + (((unsigned)sb.w) << 9) + lb);
        int4 na = sa, nb = sb;
        if (beg + 8 < end) {
            na = *(const int4*)(csr + beg + 8);
            nb = *(const int4*)(csr + beg + 12);
        }
        for (int e = beg; e < end; ) {
            half8 u0 = v0, u1 = v1, u2 = v2, u3 = v3, u4 = v4, u5 = v5, u6 = v6, u7 = v7;
            e += 8;
            if (e < end) {
                v0 = *(const half8*)(tc + (((unsigned)na.x) << 9) + lb);
                v1 = *(const half8*)(tc + (((unsigned)na.y) << 9) + lb);
                v2 = *(const half8*)(tc + (((unsigned)na.z) << 9) + lb);
                v3 = *(const half8*)(tc + (((unsigned)na.w) << 9) + lb);
                v4 = *(const half8*)(tc + (((unsigned)nb.x) << 9) + lb);
                v5 = *(const half8*)(tc + (((unsigned)nb.y) << 9) + lb);
                v6 = *(const half8*)(tc + (((unsigned)nb.z) << 9) + lb);
                v7 = *(const half8*)(tc + (((unsigned)nb.w) << 9) + lb);
                if (e + 8 < end) {
                    na = *(const int4*)(csr + e + 8);
                    nb = *(const int4*)(csr + e + 12);
                }
            }
            #pragma unroll
            for (int c = 0; c < 8; ++c) {
                a0[c] = fmaf((float)u0[c], din, a0[c]);
                a1[c] = fmaf((float)u1[c], din, a1[c]);
                a2[c] = fmaf((float)u2[c], din, a2[c]);
                a3[c] = fmaf((float)u3[c], din, a3[c]);
                a0[c] = fmaf((float)u4[c], din, a0[c]);
                a1[c] = fmaf((float)u5[c], din, a1[c]);
                a2[c] = fmaf((float)u6[c], din, a2[c]);
                a3[c] = fmaf((float)u7[c], din, a3[c]);
            }
        }
    }

    half8 sv = ((const half8*)(t + (size_t)node * DE))[lane];
    f32x4 bv0 = ((const f32x4*)bias)[lane * 2];
    f32x4 bv1 = ((const f32x4*)bias)[lane * 2 + 1];
    f32x4 o0, o1;
    #pragma unroll
    for (int c = 0; c < 8; ++c) {
        float b = (c < 4) ? bv0[c] : bv1[c - 4];
        float acc = (a0[c] + a1[c]) + (a2[c] + a3[c]);
        float o = fmaf((float)sv[c], din, acc) + b;
        if (c < 4) o0[c] = o; else o1[c - 4] = o;
    }
    ((f32x4*)(out + (size_t)node * DE))[lane * 2]     = o0;
    ((f32x4*)(out + (size_t)node * DE))[lane * 2 + 1] = o1;
}

// ---------------- MFMA heads: emb fp32 -> in-register bf16 hi/lo split -> MFMA ----------

__global__ __launch_bounds__(256) void k_heads_mfma(
    const float* __restrict__ emb,
    const bf16_t* __restrict__ Wth, const bf16_t* __restrict__ Wtl,
    const float* __restrict__ bc,
    float* __restrict__ oe, float* __restrict__ oh, float* __restrict__ og) {
    const int wave = threadIdx.x >> 6, lane = threadIdx.x & 63;
    const int quad = lane >> 4, l16 = lane & 15;
    const int row0 = blockIdx.x * 64 + wave * 16;

    f32x4 acc[5];
    #pragma unroll
    for (int j = 0; j < 5; ++j)
        #pragma unroll
        for (int r = 0; r < 4; ++r) acc[j][r] = 0.f;

    const int arow = row0 + l16;
    const size_t abase = (size_t)((arow < NN) ? arow : 0) * 256 + quad * 8;  // clamp pad rows
    #pragma unroll
    for (int ks = 0; ks < 256; ks += 32) {
        f32x4 e0 = *(const f32x4*)(emb + abase + ks);
        f32x4 e1 = *(const f32x4*)(emb + abase + ks + 4);
        bf16x8 ah, al;
        #pragma unroll
        for (int c = 0; c < 4; ++c) {
            float f = e0[c];
            bf16_t h = (bf16_t)f;
            ah[c] = h;
            al[c] = (bf16_t)(f - (float)h);
            float g = e1[c];
            bf16_t h2 = (bf16_t)g;
            ah[4 + c] = h2;
            al[4 + c] = (bf16_t)(g - (float)h2);
        }
        #pragma unroll
        for (int j = 0; j < 5; ++j) {
            const size_t bbase = (size_t)(j * 16 + l16) * 256 + ks + quad * 8;
            bf16x8 bh = *(const bf16x8*)(Wth + bbase);
            bf16x8 bl = *(const bf16x8*)(Wtl + bbase);
            acc[j] = __builtin_amdgcn_mfma_f32_16x16x32_bf16(ah, bh, acc[j], 0, 0, 0);
            acc[j] = __builtin_amdgcn_mfma_f32_16x16x32_bf16(ah, bl, acc[j], 0, 0, 0);
            acc[j] = __builtin_amdgcn_mfma_f32_16x16x32_bf16(al, bh, acc[j], 0, 0, 0);
        }
    }

    #pragma unroll
    for (int j = 0; j < 5; ++j) {
        int col = j * 16 + l16;
        if (col < 72) {
            float b = bc[col];
            #pragma unroll
            for (int r = 0; r < 4; ++r) {
                int row = row0 + quad * 4 + r;
                if (row < NN) {
                    float v = acc[j][r] + b;
                    if (col < 7)       oe[(size_t)row * 7 + col] = v;
                    else if (col < 15) oh[(size_t)row * 8 + (col - 7)] = v;
                    else               og[(size_t)row * 57 + (col - 15)] = v;
                }
            }
        }
    }
}

// ---------------- launch ----------------

extern "C" void kernel_launch(void* const* d_in, const int* in_sizes, int n_in,
                              void* d_out, int out_size, void* d_ws, size_t ws_size,
                              hipStream_t stream) {
    const float* x   = (const float*)d_in[0];
    const int*   ei  = (const int*)d_in[1];
    const float* W1  = (const float*)d_in[2];
    const float* b1  = (const float*)d_in[3];
    const float* W2  = (const float*)d_in[4];
    const float* b2  = (const float*)d_in[5];
    const float* W3  = (const float*)d_in[6];
    const float* b3  = (const float*)d_in[7];
    const float* We  = (const float*)d_in[8];
    const float* be  = (const float*)d_in[9];
    const float* Wh  = (const float*)d_in[10];
    const float* bh  = (const float*)d_in[11];
    const float* Wg  = (const float*)d_in[12];
    const float* bg  = (const float*)d_in[13];

    const int* e_src = ei;
    const int* e_dst = ei + NE;

    // workspace layout (~110 MB):
    //   buf0: GEMM outputs t' (fp16 NNP x 512)
    //   buf1: Xf16 (prep), then agg outputs / next GEMM A (fp16) -- X dead after GEMM1
    half_t* buf0 = (half_t*)d_ws;
    half_t* buf1 = buf0 + (size_t)NNP * DH;
    half_t* B1h  = buf1 + (size_t)NNP * DH;             // [512,512] f16
    half_t* B2h  = B1h + (size_t)DIN * DH;
    half_t* B3h  = B2h + (size_t)DH * DH;               // [256,512] f16
    bf16_t* Wth  = (bf16_t*)(B3h + (size_t)DE * DH);
    bf16_t* Wtl  = Wth + 80 * 256;
    float*  bc   = (float*)(Wtl + 80 * 256);            // 80 fp32 (pad 128)
    int*   indeg  = (int*)(bc + 128);
    int*   rowptr = indeg + 50048;                      // 50001 used
    int*   cursor = rowptr + 50048;
    float* dis    = (float*)(cursor + 50048);           // NNP floats (pad+sentinel = 0)
    int*   csr    = (int*)(dis + 50048);                // CSR_CAP
    int*   bsum   = csr + CSR_CAP;                      // 64
    int*   done   = bsum + 64;                          // 1 (scan barrier counter)

    float* emb   = (float*)d_out;                       // 50000*256
    float* out_e = emb + (size_t)NN * DE;               // 50000*7
    float* out_h = out_e + (size_t)NN * 7;              // 50000*8
    float* out_g = out_h + (size_t)NN * 8;              // 50000*57

    // 1) prep: zero indeg, then all input-only transforms in one wide launch
    hipMemsetAsync(indeg, 0, NN * sizeof(int), stream);
    k_prep<<<PB_TOTAL, 256, 0, stream>>>(x, buf1, e_dst, indeg, csr,
                                         W1, B1h, W2, B2h, W3, B3h,
                                         We, be, Wh, bh, Wg, bg, Wth, Wtl, bc, done);
    // 2) single-kernel scan + CSR fill
    k_scan<<<SCAN_BLOCKS, 1024, 0, stream>>>(indeg, rowptr, cursor, dis, bsum, done);
    k_fill<<<(NE + 255) / 256, 256, 0, stream>>>(e_src, e_dst, cursor, csr, NE);

    const int gy = NNP / 128;  // 391

    // 3) layer 1: fp16 single-term GEMM (X fp16), dis-scaled fp16 out
    k_gemm_f16<<<dim3(DH / 256, gy), 512, 0, stream>>>(buf1, B1h, dis, buf0, DH, DIN);
    k_agg16<<<NN / 2, 128, 0, stream>>>(buf0, rowptr, csr, dis, b1, buf1);

    // 4) layer 2: fp16 single-term GEMM, dis-scaled fp16 out
    k_gemm_f16<<<dim3(DH / 256, gy), 512, 0, stream>>>(buf1, B2h, dis, buf0, DH, DH);
    k_agg16<<<NN / 2, 128, 0, stream>>>(buf0, rowptr, csr, dis, b2, buf1);

    // 5) layer 3: fp16 single-term GEMM -> t3' (NNP x 256), then agg -> fp32 emb
    k_gemm_f16<<<dim3(DE / 256, gy), 512, 0, stream>>>(buf1, B3h, dis, buf0, DE, DH);
    k_agg_f32<<<NN / 4, 128, 0, stream>>>(buf0, rowptr, csr, dis, b3, emb);

    // 6) heads via MFMA (reads fp32 emb, splits in-register)
    k_heads_mfma<<<NNP / 64, 256, 0, stream>>>(emb, Wth, Wtl, bc, out_e, out_h, out_g);
}